// Round 7
// baseline (926.847 us; speedup 1.0000x reference)
//
#include <hip/hip_runtime.h>
#include <hip/hip_bf16.h>
#include <cfloat>

#define N_TOK   32768
#define K_CODES 8192
#define D_DIM   256
#define BTOK    128        // tokens per bulk block
#define CHUNK   128        // codes per chunk
#define NSPLIT  3          // code-range splits in bulk (uneven: 22/21/21 chunks)
#define CTAU_M  3.0e-5f    // contested if (m1-m2) < this (acc units)
#define CAND_MM 2.4e-5f    // rescue candidate window (acc units)
#define MAXCAND 16
#define RBTOK   32         // tokens per rescue block
#define NRS     8          // code splits in rescue
#define RSPLIT  (K_CODES / NRS)

typedef __attribute__((ext_vector_type(4)))  short bf16x4;
typedef __attribute__((ext_vector_type(8)))  short bf16x8;
typedef __attribute__((ext_vector_type(16))) float f32x16;

// ws layout (bytes) — as before; m1a/m2a/i1a regions sized for x4, NSPLIT=3 fits.
//   0      double loss_sum ; 8 uint ccount (+pad)
//   16     float e2np[8192]
//   32784  float e2h[8192]      0.5*e2np
//   65552  float Cnp[32768]
//   196624 float m1f[32768]
//   327696 int   idxf[32768]
//   458768 int   clist[32768]
//   589840 uint  ccnt_g[32768]   -> end 720912
//
// d_out scratch (33,685,516 B buffer; fully rewritten by out_loss/finalize after
// all scratch reads complete — stream-ordered):
//   0        short ehi[8192*256]    (4,194,304)
//   4194304  short elo[8192*256]    (4,194,304)
//   8388608  short zhi[32768*256]   (16,777,216)
//   25165824 float m1a[32768*4]     (524,288)
//   25690112 float m2a[32768*4]     (524,288)
//   26214400 int   i1a[32768*4]     (524,288)
//   26738688 int   cand_g[32768*16] (2,097,152) -> end 28,835,840 < 33,685,516

// ======== numpy bit-exact fp32 emulation (NO fma contraction) ========
__device__ __forceinline__ float np_sumsq256(const float* __restrict__ row) {
    #pragma clang fp contract(off)
    float blk[2];
    #pragma unroll
    for (int b = 0; b < 2; b++) {
        const float* x = row + b * 128;
        float r[8];
        #pragma unroll
        for (int j = 0; j < 8; j++) { float v = x[j]; r[j] = v * v; }
        for (int i = 8; i < 128; i += 8) {
            #pragma unroll
            for (int j = 0; j < 8; j++) { float v = x[i + j]; r[j] += v * v; }
        }
        blk[b] = ((r[0] + r[1]) + (r[2] + r[3])) + ((r[4] + r[5]) + (r[6] + r[7]));
    }
    return blk[0] + blk[1];
}

__device__ __forceinline__ float np_einsum256(const float* __restrict__ a,
                                              const float* __restrict__ b) {
    #pragma clang fp contract(off)
    float A0 = 0.f, A1 = 0.f, A2 = 0.f, A3 = 0.f;
    for (int m = 0; m < 256; m += 16) {
        A0 = a[m+ 0]*b[m+ 0] + (a[m+ 4]*b[m+ 4] + (a[m+ 8]*b[m+ 8] + (a[m+12]*b[m+12] + A0)));
        A1 = a[m+ 1]*b[m+ 1] + (a[m+ 5]*b[m+ 5] + (a[m+ 9]*b[m+ 9] + (a[m+13]*b[m+13] + A1)));
        A2 = a[m+ 2]*b[m+ 2] + (a[m+ 6]*b[m+ 6] + (a[m+10]*b[m+10] + (a[m+14]*b[m+14] + A2)));
        A3 = a[m+ 3]*b[m+ 3] + (a[m+ 7]*b[m+ 7] + (a[m+11]*b[m+11] + (a[m+15]*b[m+15] + A3)));
    }
    return (A0 + A1) + (A2 + A3);
}

__device__ __forceinline__ float np_dtilde(float Cn, float e2k, float g) {
    #pragma clang fp contract(off)
    float t = Cn + e2k;
    float d = t - 2.0f * g;
    return d;
}

// ======== bf16 split helpers ========
__device__ __forceinline__ unsigned short bf16_rne(float f) {
    unsigned u = __float_as_uint(f);
    unsigned r = u + 0x7fffu + ((u >> 16) & 1u);
    return (unsigned short)(r >> 16);
}
__device__ __forceinline__ void split_bf16(float f, short& hi, short& lo) {
    unsigned short h = bf16_rne(f);
    hi = (short)h;
    float hf = __uint_as_float(((unsigned)h) << 16);
    lo = (short)bf16_rne(f - hf);
}
// lo granule from stored hi granule + fp32 source.
// v_cvt_pk_bf16_f32 route: RNE, bit-identical to bf16_rne for finite normals
// (shared by bulk + rescue so their approx scores stay mutually bit-consistent).
__device__ __forceinline__ bf16x8 lo8(bf16x8 h, float4 a, float4 b) {
    float f[8] = {a.x, a.y, a.z, a.w, b.x, b.y, b.z, b.w};
    bf16x8 r;
    #pragma unroll
    for (int i = 0; i < 8; i += 2) {
        float d0 = f[i]     - __uint_as_float(((unsigned)(unsigned short)h[i])     << 16);
        float d1 = f[i + 1] - __uint_as_float(((unsigned)(unsigned short)h[i + 1]) << 16);
        __hip_bfloat162 p = __float22bfloat162_rn(make_float2(d0, d1));
        unsigned u; __builtin_memcpy(&u, &p, 4);
        r[i]     = (short)(u & 0xffffu);
        r[i + 1] = (short)(u >> 16);
    }
    return r;
}

#define MFMA3(A, ah, al, bh, bl) \
    A = __builtin_amdgcn_mfma_f32_32x32x16_bf16(ah, bh, A, 0, 0, 0); \
    A = __builtin_amdgcn_mfma_f32_32x32x16_bf16(ah, bl, A, 0, 0, 0); \
    A = __builtin_amdgcn_mfma_f32_32x32x16_bf16(al, bh, A, 0, 0, 0);

// ---------------- prep kernels ----------------
__global__ __launch_bounds__(256) void prep_e_kernel(
    const float* __restrict__ emb, float* __restrict__ e2np,
    float* __restrict__ e2h, unsigned* __restrict__ ccount,
    double* __restrict__ loss_sum)
{
    int k = blockIdx.x * 256 + threadIdx.x;
    float v = np_sumsq256(emb + (size_t)k * D_DIM);
    e2np[k] = v;
    e2h[k]  = 0.5f * v;
    if (k == 0) { *ccount = 0u; *loss_sum = 0.0; }
}

__global__ __launch_bounds__(256) void prep_z_kernel(
    const float* __restrict__ z, float* __restrict__ Cnp)
{
    int t = blockIdx.x * 256 + threadIdx.x;
    Cnp[t] = np_sumsq256(z + (size_t)t * D_DIM);
}

// ---------------- one-time conversions into d_out scratch ----------------
__global__ __launch_bounds__(256) void cvt_e_kernel(
    const float* __restrict__ src, short* __restrict__ hi, short* __restrict__ lo)
{
    size_t p = ((size_t)blockIdx.x * 256 + threadIdx.x) * 8;
    float4 v0 = *(const float4*)(src + p);
    float4 v1 = *(const float4*)(src + p + 4);
    short h[8], l[8];
    split_bf16(v0.x, h[0], l[0]); split_bf16(v0.y, h[1], l[1]);
    split_bf16(v0.z, h[2], l[2]); split_bf16(v0.w, h[3], l[3]);
    split_bf16(v1.x, h[4], l[4]); split_bf16(v1.y, h[5], l[5]);
    split_bf16(v1.z, h[6], l[6]); split_bf16(v1.w, h[7], l[7]);
    bf16x8 vh = {h[0],h[1],h[2],h[3],h[4],h[5],h[6],h[7]};
    bf16x8 vl = {l[0],l[1],l[2],l[3],l[4],l[5],l[6],l[7]};
    *(bf16x8*)(hi + p) = vh;
    *(bf16x8*)(lo + p) = vl;
}

__global__ __launch_bounds__(256) void cvt_zhi_kernel(
    const float* __restrict__ src, short* __restrict__ hi)
{
    size_t p = ((size_t)blockIdx.x * 256 + threadIdx.x) * 8;
    float4 v0 = *(const float4*)(src + p);
    float4 v1 = *(const float4*)(src + p + 4);
    bf16x8 vh = {(short)bf16_rne(v0.x), (short)bf16_rne(v0.y),
                 (short)bf16_rne(v0.z), (short)bf16_rne(v0.w),
                 (short)bf16_rne(v1.x), (short)bf16_rne(v1.y),
                 (short)bf16_rne(v1.z), (short)bf16_rne(v1.w)};
    *(bf16x8*)(hi + p) = vh;
}

// LDS short-offsets (bulk, 16-d stages): each buffer = 8192 shorts (16 KB).
// ESH=0(2048) ESL=2048 ZSH=4096 ZSL=6144; row stride 16 shorts, 2 granules/row.
// No XOR swizzle needed: both lane-halves read both granule positions -> b128
// bank floor by construction.
#define B_ESH 0
#define B_ESL 2048
#define B_ZSH 4096
#define B_ZSL 6144
#define BUFSZ 8192

// ---------------- bulk mfma scan: 128 tok x (21|22 chunks x 128 codes) ----------------
// 256 threads / 4 waves, wave tile 64 codes x 64 tokens (acc[2][2]) ->
// 8 ds_reads per 12 MFMAs (0.67 reads/MFMA vs 1.0 before). 16-d stages halve the
// buffer (32 KB dbuf, ~45 KB block LDS) -> 3 blocks/CU, 12 waves/CU with 3-way
// independent anti-phase overlap. NSPLIT=3 -> 768 blocks = exactly 3/CU (no tail).
// Depth-2 reg prefetch + T4 barrier (lgkmcnt-only, vmcnt never drained) + T5
// setprio around the MFMA cluster.
__global__ __launch_bounds__(256, 3) void bulk_kernel(
    const float* __restrict__ zf, const short* __restrict__ zhi,
    const short* __restrict__ ehi, const short* __restrict__ elo,
    const float* __restrict__ e2h,
    float* __restrict__ m1a, float* __restrict__ m2a, int* __restrict__ i1a)
{
    __shared__ __align__(16) short smem[2][BUFSZ];   // 2 x 16 KB
    __shared__ float e2sall[22 * CHUNK];             // up to 22 chunks = 11 KB
    __shared__ float s1m[BTOK], s2m[BTOK];
    __shared__ int   i1m[BTOK];

    const int tid  = threadIdx.x;
    const int lane = tid & 63;
    const int w    = tid >> 6;          // 0..3
    const int wt   = w & 1;             // token 64-tile
    const int wc   = w >> 1;            // code 64-tile
    const int g     = blockIdx.x & 255;
    const int split = blockIdx.x >> 8;  // 0..2
    const int tok0  = g * BTOK;
    const int cbase = split * 21 + (split ? 1 : 0);   // chunk base: 0,22,43
    const int nch   = split ? 21 : 22;                // chunks: 22,21,21
    const int cs0   = cbase * CHUNK;

    // staging: thread (r,gq) = (tid>>1, tid&1): one e-slot (hi+lo) + one z-slot
    const int r0 = tid >> 1, q0 = tid & 1;
    const int so0 = r0 * 16 + q0 * 8;   // shorts; linear, no swizzle

    // mfma read addressing (shorts): granule = hh directly
    const int l31 = lane & 31, hh = lane >> 5;
    const int a0 = (wc * 64 + l31) * 16 + hh * 8;   // code subtile 0
    const int a1 = a0 + 512;                        // +32 rows
    const int b0 = (wt * 64 + l31) * 16 + hh * 8;   // token subtile 0
    const int b1 = b0 + 512;

    float m1[2] = {-FLT_MAX, -FLT_MAX}, m2[2] = {-FLT_MAX, -FLT_MAX};
    int   k1[2] = {0x7fffffff, 0x7fffffff};

    // depth-2 prefetch register slots (static names — rule #20)
    bf16x8 ehA, elA, zhA;  float4 zfaA, zfbA;
    bf16x8 ehB, elB, zhB;  float4 zfaB, zfbB;

    f32x16 acc[2][2];
    #pragma unroll
    for (int i = 0; i < 2; i++)
        #pragma unroll
        for (int j = 0; j < 2; j++)
            #pragma unroll
            for (int r = 0; r < 16; r++) acc[i][j][r] = 0.f;

    const int NST = nch * 16;   // 16-d stages per chunk

    auto ISSUE_A = [&](int s) {
        const int code0 = cs0 + (s >> 4) * CHUNK;
        const int d0 = (s & 15) * 16;
        const size_t ei = ((size_t)(code0 + r0) << 8) + d0 + (q0 << 3);
        const size_t zi = ((size_t)(tok0 + r0) << 8) + d0 + (q0 << 3);
        ehA = *(const bf16x8*)(ehi + ei);
        elA = *(const bf16x8*)(elo + ei);
        zhA = *(const bf16x8*)(zhi + zi);
        zfaA = *(const float4*)(zf + zi);
        zfbA = *(const float4*)(zf + zi + 4);
    };
    auto ISSUE_B = [&](int s) {
        const int code0 = cs0 + (s >> 4) * CHUNK;
        const int d0 = (s & 15) * 16;
        const size_t ei = ((size_t)(code0 + r0) << 8) + d0 + (q0 << 3);
        const size_t zi = ((size_t)(tok0 + r0) << 8) + d0 + (q0 << 3);
        ehB = *(const bf16x8*)(ehi + ei);
        elB = *(const bf16x8*)(elo + ei);
        zhB = *(const bf16x8*)(zhi + zi);
        zfaB = *(const float4*)(zf + zi);
        zfbB = *(const float4*)(zf + zi + 4);
    };

    auto STORE_A = [&](int buf) {
        bf16x8 zl0 = lo8(zhA, zfaA, zfbA);
        short* sm = smem[buf];
        *(bf16x8*)(sm + B_ESH + so0) = ehA;
        *(bf16x8*)(sm + B_ESL + so0) = elA;
        *(bf16x8*)(sm + B_ZSH + so0) = zhA;
        *(bf16x8*)(sm + B_ZSL + so0) = zl0;
    };
    auto STORE_B = [&](int buf) {
        bf16x8 zl0 = lo8(zhB, zfaB, zfbB);
        short* sm = smem[buf];
        *(bf16x8*)(sm + B_ESH + so0) = ehB;
        *(bf16x8*)(sm + B_ESL + so0) = elB;
        *(bf16x8*)(sm + B_ZSH + so0) = zhB;
        *(bf16x8*)(sm + B_ZSL + so0) = zl0;
    };

    // prologue: e2 table for this split; stages 0 (A) and 1 (B) in flight;
    // stage 0 into buffer 0. One full __syncthreads here is fine.
    for (int idx = tid; idx < nch * CHUNK; idx += 256)
        e2sall[idx] = e2h[cs0 + idx];
    ISSUE_A(0);
    ISSUE_B(1);
    STORE_A(0);
    __syncthreads();

    #pragma unroll 2
    for (int s = 0; s < NST; s++) {
        const int cur = s & 1;
        if (s + 2 < NST) {                 // refill the slot consumed last iter
            if (cur == 0) ISSUE_A(s + 2); else ISSUE_B(s + 2);
        }
        {
            const short* sm = smem[cur];
            bf16x8 a0h = *(const bf16x8*)(sm + B_ESH + a0);
            bf16x8 a0l = *(const bf16x8*)(sm + B_ESL + a0);
            bf16x8 a1h = *(const bf16x8*)(sm + B_ESH + a1);
            bf16x8 a1l = *(const bf16x8*)(sm + B_ESL + a1);
            bf16x8 b0h = *(const bf16x8*)(sm + B_ZSH + b0);
            bf16x8 b0l = *(const bf16x8*)(sm + B_ZSL + b0);
            bf16x8 b1h = *(const bf16x8*)(sm + B_ZSH + b1);
            bf16x8 b1l = *(const bf16x8*)(sm + B_ZSL + b1);
            __builtin_amdgcn_s_setprio(1);
            MFMA3(acc[0][0], a0h, a0l, b0h, b0l);
            MFMA3(acc[0][1], a0h, a0l, b1h, b1l);
            MFMA3(acc[1][0], a1h, a1l, b0h, b0l);
            MFMA3(acc[1][1], a1h, a1l, b1h, b1l);
            __builtin_amdgcn_s_setprio(0);
        }
        if ((s & 15) == 15) {
            // epilogue for chunk c = s>>4: a = acc - e2/2, top-2 insert, re-zero
            const int c = s >> 4;
            const int code0 = cs0 + c * CHUNK;
            const float* e2c = e2sall + c * CHUNK;
            #pragma unroll
            for (int i = 0; i < 2; i++) {
                float ev[16];
                #pragma unroll
                for (int r = 0; r < 16; r++)
                    ev[r] = e2c[wc * 64 + i * 32 + hh * 4 + (r & 3) + ((r >> 2) << 3)];
                #pragma unroll
                for (int j = 0; j < 2; j++) {
                    #pragma unroll
                    for (int r = 0; r < 16; r++) {
                        float a = acc[i][j][r] - ev[r];
                        int code = code0 + wc * 64 + i * 32 + hh * 4 + (r & 3) + ((r >> 2) << 3);
                        if (a > m1[j]) { m2[j] = m1[j]; m1[j] = a; k1[j] = code; }
                        else if (a > m2[j]) m2[j] = a;
                    }
                }
            }
            #pragma unroll
            for (int i = 0; i < 2; i++)
                #pragma unroll
                for (int j = 0; j < 2; j++)
                    #pragma unroll
                    for (int r = 0; r < 16; r++) acc[i][j][r] = 0.f;
        }
        if (s + 1 < NST) {                 // store stage s+1 (loads issued iter s-1)
            if (cur == 0) STORE_B(cur ^ 1); else STORE_A(cur ^ 1);
        }
        // T4 barrier: LDS-write visibility only; vmcnt NOT drained — prefetch
        // loads stay in flight across the barrier. sched_barrier fences
        // next-iteration ds_reads from hoisting above (rule #18).
        asm volatile("s_waitcnt lgkmcnt(0)" ::: "memory");
        __builtin_amdgcn_s_barrier();
        __builtin_amdgcn_sched_barrier(0);
    }

    // merge lane halves (hh=0 vs hh=1: same token column, different code rows)
    #pragma unroll
    for (int j = 0; j < 2; j++) {
        float o1 = __shfl_xor(m1[j], 32);
        float o2 = __shfl_xor(m2[j], 32);
        int   oi = __shfl_xor(k1[j], 32);
        bool take = (o1 > m1[j]) || (o1 == m1[j] && oi < k1[j]);
        float w1 = take ? o1 : m1[j];
        int   wi = take ? oi : k1[j];
        float ls = take ? m1[j] : o1;
        m2[j] = fmaxf(fmaxf(m2[j], o2), ls);
        m1[j] = w1; k1[j] = wi;
    }
    // cross-wave merge: wc=0 and wc=1 share tokens (same wt)
    __syncthreads();
    if (wc == 0 && lane < 32) {
        #pragma unroll
        for (int j = 0; j < 2; j++) {
            int tl = wt * 64 + j * 32 + lane;
            s1m[tl] = m1[j]; s2m[tl] = m2[j]; i1m[tl] = k1[j];
        }
    }
    __syncthreads();
    if (wc == 1 && lane < 32) {
        #pragma unroll
        for (int j = 0; j < 2; j++) {
            int tl = wt * 64 + j * 32 + lane;
            float a1 = s1m[tl], a2 = s2m[tl]; int ai = i1m[tl];
            bool take = (a1 > m1[j]) || (a1 == m1[j] && ai < k1[j]);
            float w1 = take ? a1 : m1[j];
            int   wi = take ? ai : k1[j];
            float ls = take ? m1[j] : a1;
            float w2 = fmaxf(fmaxf(m2[j], a2), ls);
            size_t t = (size_t)(tok0 + tl) * NSPLIT + split;
            m1a[t] = w1; m2a[t] = w2; i1a[t] = wi;
        }
    }
}

// ---------------- merge splits, detect contested, zero cand counters ----------------
__global__ __launch_bounds__(256) void merge_kernel(
    const float* __restrict__ m1a, const float* __restrict__ m2a,
    const int* __restrict__ i1a, float* __restrict__ m1f,
    int* __restrict__ idxf, int* __restrict__ clist,
    unsigned* __restrict__ ccount, unsigned* __restrict__ ccnt_g)
{
    int t = blockIdx.x * 256 + threadIdx.x;
    ccnt_g[t] = 0u;
    float w1 = m1a[t * NSPLIT], w2 = m2a[t * NSPLIT];
    int   wi = i1a[t * NSPLIT];
    #pragma unroll
    for (int s = 1; s < NSPLIT; s++) {
        float a1 = m1a[t * NSPLIT + s], a2 = m2a[t * NSPLIT + s];
        int   ai = i1a[t * NSPLIT + s];
        bool take = (a1 > w1) || (a1 == w1 && ai < wi);
        float n1 = take ? a1 : w1;
        int   ni = take ? ai : wi;
        float ls = take ? w1 : a1;
        w2 = fmaxf(fmaxf(w2, a2), ls);
        w1 = n1; wi = ni;
    }
    idxf[t] = wi; m1f[t] = w1;
    if (w1 - w2 < CTAU_M) {
        unsigned p = atomicAdd(ccount, 1u);
        clist[p] = t;
    }
}

// LDS short-offsets (rescue): ESH=0 ESL=4096 ZSH=8192 ZSL=9216
#define R_ESH 0
#define R_ESL 4096
#define R_ZSH 8192
#define R_ZSL 9216

// ---------------- rescue: parallel mfma candidate sweep (32 tok x 1024 codes) ----------------
__global__ __launch_bounds__(256) void rescue_kernel(
    const float* __restrict__ zf, const short* __restrict__ zhi,
    const short* __restrict__ ehi, const short* __restrict__ elo,
    const float* __restrict__ e2h, const float* __restrict__ m1f,
    const unsigned* __restrict__ ccount, const int* __restrict__ clist,
    unsigned* __restrict__ ccnt_g, int* __restrict__ cand_g)
{
    const unsigned count = *ccount;
    const unsigned base  = blockIdx.x * RBTOK;
    if (base >= count) return;
    const int nt = min(RBTOK, (int)(count - base));
    const int sp = blockIdx.y;

    __shared__ __align__(16) short rsm[10240];   // 20 KB
    __shared__ int   tls[RBTOK];
    __shared__ float thr[RBTOK];
    __shared__ float e2s[CHUNK];

    const int tid  = threadIdx.x;
    const int lane = tid & 63;
    const int w    = tid >> 6;

    if (tid < RBTOK) {
        int s = (tid < nt) ? tid : (nt - 1);
        int t = clist[base + s];
        tls[tid] = t;
        thr[tid] = (tid < nt) ? (m1f[t] - CAND_MM) : FLT_MAX;
    }
    __syncthreads();

    const int l31 = lane & 31, hh = lane >> 5;
    const float mythr = thr[l31];
    const int   mytok = tls[l31];
    const int swz = (l31 >> 1) & 3;
    const int arow = (w * 32 + l31) * 32;
    const int brow = l31 * 32;
    const int a0 = arow + ((hh ^ swz) << 3);
    const int a1 = arow + (((2 + hh) ^ swz) << 3);
    const int b0 = brow + ((hh ^ swz) << 3);
    const int b1 = brow + (((2 + hh) ^ swz) << 3);

    // e staging: 2 slots/thread (pure copies); z: tid<128, one slot each (hi+lo)
    const int er0 = tid >> 2, eq0 = tid & 3;
    const int er1 = er0 + 64;
    const int eso0 = er0 * 32 + ((eq0 ^ ((er0 >> 1) & 3)) << 3);
    const int eso1 = er1 * 32 + ((eq0 ^ ((er1 >> 1) & 3)) << 3);
    const int zr = (tid & 127) >> 2, zq = tid & 3;
    const int zso = zr * 32 + ((zq ^ ((zr >> 1) & 3)) << 3);

    for (int c = 0; c < RSPLIT / CHUNK; c++) {
        const int code0 = sp * RSPLIT + c * CHUNK;
        const float e2v = (tid < CHUNK) ? e2h[code0 + tid] : 0.f;
        f32x16 acc;
        #pragma unroll
        for (int r = 0; r < 16; r++) acc[r] = 0.f;

        for (int st = 0; st < 8; st++) {
            const int d0 = st * 32;
            const size_t ei0 = ((size_t)(code0 + er0) << 8) + d0 + (eq0 << 3);
            const size_t ei1 = ((size_t)(code0 + er1) << 8) + d0 + (eq0 << 3);
            bf16x8 eh0 = *(const bf16x8*)(ehi + ei0);
            bf16x8 el0 = *(const bf16x8*)(elo + ei0);
            bf16x8 eh1 = *(const bf16x8*)(ehi + ei1);
            bf16x8 el1 = *(const bf16x8*)(elo + ei1);
            bf16x8 zh = {}, zl = {};
            if (tid < 128) {
                const size_t zi = ((size_t)tls[zr] << 8) + d0 + (zq << 3);
                zh = *(const bf16x8*)(zhi + zi);
                float4 za = *(const float4*)(zf + zi);
                float4 zb = *(const float4*)(zf + zi + 4);
                zl = lo8(zh, za, zb);
            }
            __syncthreads();
            *(bf16x8*)(rsm + R_ESH + eso0) = eh0;
            *(bf16x8*)(rsm + R_ESL + eso0) = el0;
            *(bf16x8*)(rsm + R_ESH + eso1) = eh1;
            *(bf16x8*)(rsm + R_ESL + eso1) = el1;
            if (tid < 128) {
                *(bf16x8*)(rsm + R_ZSH + zso) = zh;
                *(bf16x8*)(rsm + R_ZSL + zso) = zl;
            }
            if (st == 0 && tid < CHUNK) e2s[tid] = e2v;
            __syncthreads();
            {
                bf16x8 ah = *(const bf16x8*)(rsm + R_ESH + a0);
                bf16x8 al = *(const bf16x8*)(rsm + R_ESL + a0);
                bf16x8 bh = *(const bf16x8*)(rsm + R_ZSH + b0);
                bf16x8 bl = *(const bf16x8*)(rsm + R_ZSL + b0);
                MFMA3(acc, ah, al, bh, bl);
            }
            {
                bf16x8 ah = *(const bf16x8*)(rsm + R_ESH + a1);
                bf16x8 al = *(const bf16x8*)(rsm + R_ESL + a1);
                bf16x8 bh = *(const bf16x8*)(rsm + R_ZSH + b1);
                bf16x8 bl = *(const bf16x8*)(rsm + R_ZSL + b1);
                MFMA3(acc, ah, al, bh, bl);
            }
        }
        #pragma unroll
        for (int r = 0; r < 16; r++) {
            const int local = w * 32 + hh * 4 + (r & 3) + ((r >> 2) << 3);
            float a = acc[r] - e2s[local];
            if (a >= mythr) {
                unsigned p = atomicAdd(&ccnt_g[mytok], 1u);
                if (p < MAXCAND) cand_g[(size_t)mytok * MAXCAND + p] = code0 + local;
            }
        }
    }
}

// ---------------- resolve: np-exact d over candidates, first-index min ----------------
__global__ __launch_bounds__(256) void resolve_kernel(
    const float* __restrict__ z, const float* __restrict__ emb,
    const float* __restrict__ e2np, const float* __restrict__ Cnp,
    const unsigned* __restrict__ ccount, const int* __restrict__ clist,
    const unsigned* __restrict__ ccnt_g, const int* __restrict__ cand_g,
    int* __restrict__ idxf)
{
    const unsigned count = *ccount;
    const int lane = threadIdx.x & 63;
    const int w    = threadIdx.x >> 6;
    for (unsigned c = blockIdx.x * 4 + w; c < count; c += gridDim.x * 4) {
        const int t = clist[c];
        const int n = (int)min(ccnt_g[t], (unsigned)MAXCAND);
        float bd = FLT_MAX; int bk = 0x7fffffff;
        if (lane < n) {
            const int k = cand_g[(size_t)t * MAXCAND + lane];
            float g = np_einsum256(z + (size_t)t * D_DIM, emb + (size_t)k * D_DIM);
            bd = np_dtilde(Cnp[t], e2np[k], g);
            bk = k;
        }
        #pragma unroll
        for (int off = 32; off >= 1; off >>= 1) {
            float od = __shfl_xor(bd, off);
            int   ok = __shfl_xor(bk, off);
            if (od < bd || (od == bd && ok < bk)) { bd = od; bk = ok; }
        }
        if (lane == 0 && n > 0) idxf[t] = bk;
    }
}

// ---------------- gather z_q, write out0, fp64 MSE sum ----------------
__global__ __launch_bounds__(256) void out_loss_kernel(
    const float* __restrict__ z, const float* __restrict__ emb,
    const int* __restrict__ idxf, float* __restrict__ out0,
    double* __restrict__ loss_sum)
{
    const int total4 = N_TOK * (D_DIM / 4);
    double lsum = 0.0;
    for (int p = blockIdx.x * 256 + threadIdx.x; p < total4; p += gridDim.x * 256) {
        const int n  = p >> 6;
        const int d4 = p & 63;
        const int k  = idxf[n];
        float4 zv = ((const float4*)z)[p];
        float4 ev = ((const float4*)(emb + (size_t)k * D_DIM))[d4];
        float dx = ev.x - zv.x, dy = ev.y - zv.y,
              dz = ev.z - zv.z, dw = ev.w - zv.w;
        float4 o;
        o.x = zv.x + dx; o.y = zv.y + dy; o.z = zv.z + dz; o.w = zv.w + dw;
        ((float4*)out0)[p] = o;
        lsum += (double)dx * dx + (double)dy * dy
              + (double)dz * dz + (double)dw * dw;
    }
    #pragma unroll
    for (int off = 32; off >= 1; off >>= 1) lsum += __shfl_xor(lsum, off);
    __shared__ double wsum[4];
    const int wv = threadIdx.x >> 6;
    if ((threadIdx.x & 63) == 0) wsum[wv] = lsum;
    __syncthreads();
    if (threadIdx.x == 0)
        atomicAdd(loss_sum, wsum[0] + wsum[1] + wsum[2] + wsum[3]);
}

__global__ __launch_bounds__(256) void finalize_kernel(
    const int* __restrict__ idxf, const double* __restrict__ loss_sum,
    float* __restrict__ out)
{
    const int t = blockIdx.x * 256 + threadIdx.x;
    if (t < N_TOK) out[8388611 + t] = (float)idxf[t];
    if (t == 0) {
        double mse = *loss_sum * (1.0 / 8388608.0);
        out[8388608] = (float)(1.25 * mse);
        out[8388609] = (float)(0.25 * mse);
        out[8388610] = (float)mse;
    }
}

extern "C" void kernel_launch(void* const* d_in, const int* in_sizes, int n_in,
                              void* d_out, int out_size, void* d_ws, size_t ws_size,
                              hipStream_t stream)
{
    const float* z   = (const float*)d_in[0];
    const float* emb = (const float*)d_in[1];
    float* out = (float*)d_out;
    char*  ws  = (char*)d_ws;
    char*  ob  = (char*)d_out;

    // big scratch inside d_out (all reads finish before out_loss/finalize rewrite it)
    short*    ehi    = (short*)(ob + 0);
    short*    elo    = (short*)(ob + 4194304);
    short*    zhi    = (short*)(ob + 8388608);
    float*    m1a    = (float*)(ob + 25165824);
    float*    m2a    = (float*)(ob + 25690112);
    int*      i1a    = (int*)(ob + 26214400);
    int*      cand_g = (int*)(ob + 26738688);

    double*   loss_sum = (double*)(ws + 0);
    unsigned* ccount   = (unsigned*)(ws + 8);
    float*    e2np     = (float*)(ws + 16);
    float*    e2h      = (float*)(ws + 32784);
    float*    Cnp      = (float*)(ws + 65552);
    float*    m1f      = (float*)(ws + 196624);
    int*      idxf     = (int*)(ws + 327696);
    int*      clist    = (int*)(ws + 458768);
    unsigned* ccnt_g   = (unsigned*)(ws + 589840);

    prep_e_kernel<<<dim3(K_CODES / 256), dim3(256), 0, stream>>>(
        emb, e2np, e2h, ccount, loss_sum);
    prep_z_kernel<<<dim3(N_TOK / 256), dim3(256), 0, stream>>>(z, Cnp);
    cvt_e_kernel<<<dim3(K_CODES * D_DIM / 8 / 256), dim3(256), 0, stream>>>(emb, ehi, elo);
    cvt_zhi_kernel<<<dim3(N_TOK * D_DIM / 8 / 256), dim3(256), 0, stream>>>(z, zhi);
    bulk_kernel<<<dim3((N_TOK / BTOK) * NSPLIT), dim3(256), 0, stream>>>(
        z, zhi, ehi, elo, e2h, m1a, m2a, i1a);
    merge_kernel<<<dim3(N_TOK / 256), dim3(256), 0, stream>>>(
        m1a, m2a, i1a, m1f, idxf, clist, ccount, ccnt_g);
    rescue_kernel<<<dim3(N_TOK / RBTOK, NRS), dim3(256), 0, stream>>>(
        z, zhi, ehi, elo, e2h, m1f, ccount, clist, ccnt_g, cand_g);
    resolve_kernel<<<dim3(128), dim3(256), 0, stream>>>(
        z, emb, e2np, Cnp, ccount, clist, ccnt_g, cand_g, idxf);
    out_loss_kernel<<<dim3(1024), dim3(256), 0, stream>>>(
        z, emb, idxf, out, loss_sum);
    finalize_kernel<<<dim3(N_TOK / 256), dim3(256), 0, stream>>>(
        idxf, loss_sum, out);
}

// Round 8
// 818.798 us; speedup vs baseline: 1.1320x; 1.1320x over previous
//
#include <hip/hip_runtime.h>
#include <hip/hip_bf16.h>
#include <cfloat>

#define N_TOK   32768
#define K_CODES 8192
#define D_DIM   256
#define BTOK    128        // tokens per bulk block
#define CHUNK   128        // codes per chunk
#define NSPLIT  4          // code-range splits in bulk
#define SPLITK  (K_CODES / NSPLIT)
#define CTAU_M  3.0e-5f    // contested if (m1-m2) < this (acc units)
#define CAND_MM 2.4e-5f    // rescue candidate window (acc units)
#define MAXCAND 16
#define RBTOK   32         // tokens per rescue block
#define NRS     8          // code splits in rescue
#define RSPLIT  (K_CODES / NRS)

typedef __attribute__((ext_vector_type(4)))  short bf16x4;
typedef __attribute__((ext_vector_type(8)))  short bf16x8;
typedef __attribute__((ext_vector_type(16))) float f32x16;

// ws layout (bytes) — 720,912 B total:
//   0      double loss_sum ; 8 uint ccount (+pad)
//   16     float e2np[8192]
//   32784  float e2h[8192]      0.5*e2np
//   65552  float Cnp[32768]
//   196624 float m1f[32768]
//   327696 int   idxf[32768]
//   458768 int   clist[32768]
//   589840 uint  ccnt_g[32768]   -> end 720912
//
// d_out scratch (33,685,516 B buffer; fully rewritten by out_loss/finalize after
// all scratch reads complete — stream-ordered):
//   0        short ehi[8192*256]    (4,194,304)
//   4194304  short elo[8192*256]    (4,194,304)
//   8388608  short zhi[32768*256]   (16,777,216)
//   25165824 float m1a[32768*4]     (524,288)
//   25690112 float m2a[32768*4]     (524,288)
//   26214400 int   i1a[32768*4]     (524,288)
//   26738688 int   cand_g[32768*16] (2,097,152) -> end 28,835,840 < 33,685,516

// ======== numpy bit-exact fp32 emulation (NO fma contraction) ========
__device__ __forceinline__ float np_sumsq256(const float* __restrict__ row) {
    #pragma clang fp contract(off)
    float blk[2];
    #pragma unroll
    for (int b = 0; b < 2; b++) {
        const float* x = row + b * 128;
        float r[8];
        #pragma unroll
        for (int j = 0; j < 8; j++) { float v = x[j]; r[j] = v * v; }
        for (int i = 8; i < 128; i += 8) {
            #pragma unroll
            for (int j = 0; j < 8; j++) { float v = x[i + j]; r[j] += v * v; }
        }
        blk[b] = ((r[0] + r[1]) + (r[2] + r[3])) + ((r[4] + r[5]) + (r[6] + r[7]));
    }
    return blk[0] + blk[1];
}

__device__ __forceinline__ float np_einsum256(const float* __restrict__ a,
                                              const float* __restrict__ b) {
    #pragma clang fp contract(off)
    float A0 = 0.f, A1 = 0.f, A2 = 0.f, A3 = 0.f;
    for (int m = 0; m < 256; m += 16) {
        A0 = a[m+ 0]*b[m+ 0] + (a[m+ 4]*b[m+ 4] + (a[m+ 8]*b[m+ 8] + (a[m+12]*b[m+12] + A0)));
        A1 = a[m+ 1]*b[m+ 1] + (a[m+ 5]*b[m+ 5] + (a[m+ 9]*b[m+ 9] + (a[m+13]*b[m+13] + A1)));
        A2 = a[m+ 2]*b[m+ 2] + (a[m+ 6]*b[m+ 6] + (a[m+10]*b[m+10] + (a[m+14]*b[m+14] + A2)));
        A3 = a[m+ 3]*b[m+ 3] + (a[m+ 7]*b[m+ 7] + (a[m+11]*b[m+11] + (a[m+15]*b[m+15] + A3)));
    }
    return (A0 + A1) + (A2 + A3);
}

__device__ __forceinline__ float np_dtilde(float Cn, float e2k, float g) {
    #pragma clang fp contract(off)
    float t = Cn + e2k;
    float d = t - 2.0f * g;
    return d;
}

// ======== bf16 split helpers ========
__device__ __forceinline__ unsigned short bf16_rne(float f) {
    unsigned u = __float_as_uint(f);
    unsigned r = u + 0x7fffu + ((u >> 16) & 1u);
    return (unsigned short)(r >> 16);
}
__device__ __forceinline__ void split_bf16(float f, short& hi, short& lo) {
    unsigned short h = bf16_rne(f);
    hi = (short)h;
    float hf = __uint_as_float(((unsigned)h) << 16);
    lo = (short)bf16_rne(f - hf);
}
// lo granule from stored hi granule + fp32 source.
// v_cvt_pk_bf16_f32 route: RNE, bit-identical to bf16_rne for finite normals
// (shared by bulk + rescue so their approx scores stay mutually bit-consistent).
__device__ __forceinline__ bf16x8 lo8(bf16x8 h, float4 a, float4 b) {
    float f[8] = {a.x, a.y, a.z, a.w, b.x, b.y, b.z, b.w};
    bf16x8 r;
    #pragma unroll
    for (int i = 0; i < 8; i += 2) {
        float d0 = f[i]     - __uint_as_float(((unsigned)(unsigned short)h[i])     << 16);
        float d1 = f[i + 1] - __uint_as_float(((unsigned)(unsigned short)h[i + 1]) << 16);
        __hip_bfloat162 p = __float22bfloat162_rn(make_float2(d0, d1));
        unsigned u; __builtin_memcpy(&u, &p, 4);
        r[i]     = (short)(u & 0xffffu);
        r[i + 1] = (short)(u >> 16);
    }
    return r;
}

#define MFMA3(A, ah, al, bh, bl) \
    A = __builtin_amdgcn_mfma_f32_32x32x16_bf16(ah, bh, A, 0, 0, 0); \
    A = __builtin_amdgcn_mfma_f32_32x32x16_bf16(ah, bl, A, 0, 0, 0); \
    A = __builtin_amdgcn_mfma_f32_32x32x16_bf16(al, bh, A, 0, 0, 0);

// ---------------- prep kernels ----------------
__global__ __launch_bounds__(256) void prep_e_kernel(
    const float* __restrict__ emb, float* __restrict__ e2np,
    float* __restrict__ e2h, unsigned* __restrict__ ccount,
    double* __restrict__ loss_sum)
{
    int k = blockIdx.x * 256 + threadIdx.x;
    float v = np_sumsq256(emb + (size_t)k * D_DIM);
    e2np[k] = v;
    e2h[k]  = 0.5f * v;
    if (k == 0) { *ccount = 0u; *loss_sum = 0.0; }
}

__global__ __launch_bounds__(256) void prep_z_kernel(
    const float* __restrict__ z, float* __restrict__ Cnp)
{
    int t = blockIdx.x * 256 + threadIdx.x;
    Cnp[t] = np_sumsq256(z + (size_t)t * D_DIM);
}

// ---------------- one-time conversions into d_out scratch ----------------
__global__ __launch_bounds__(256) void cvt_e_kernel(
    const float* __restrict__ src, short* __restrict__ hi, short* __restrict__ lo)
{
    size_t p = ((size_t)blockIdx.x * 256 + threadIdx.x) * 8;
    float4 v0 = *(const float4*)(src + p);
    float4 v1 = *(const float4*)(src + p + 4);
    short h[8], l[8];
    split_bf16(v0.x, h[0], l[0]); split_bf16(v0.y, h[1], l[1]);
    split_bf16(v0.z, h[2], l[2]); split_bf16(v0.w, h[3], l[3]);
    split_bf16(v1.x, h[4], l[4]); split_bf16(v1.y, h[5], l[5]);
    split_bf16(v1.z, h[6], l[6]); split_bf16(v1.w, h[7], l[7]);
    bf16x8 vh = {h[0],h[1],h[2],h[3],h[4],h[5],h[6],h[7]};
    bf16x8 vl = {l[0],l[1],l[2],l[3],l[4],l[5],l[6],l[7]};
    *(bf16x8*)(hi + p) = vh;
    *(bf16x8*)(lo + p) = vl;
}

__global__ __launch_bounds__(256) void cvt_zhi_kernel(
    const float* __restrict__ src, short* __restrict__ hi)
{
    size_t p = ((size_t)blockIdx.x * 256 + threadIdx.x) * 8;
    float4 v0 = *(const float4*)(src + p);
    float4 v1 = *(const float4*)(src + p + 4);
    bf16x8 vh = {(short)bf16_rne(v0.x), (short)bf16_rne(v0.y),
                 (short)bf16_rne(v0.z), (short)bf16_rne(v0.w),
                 (short)bf16_rne(v1.x), (short)bf16_rne(v1.y),
                 (short)bf16_rne(v1.z), (short)bf16_rne(v1.w)};
    *(bf16x8*)(hi + p) = vh;
}

// LDS short-offsets (bulk): ESH=0 ESL=4096 ZSH=8192 ZSL=12288; +1024 = +32 rows
#define B_ESH 0
#define B_ESL 4096
#define B_ZSH 8192
#define B_ZSL 12288
#define TILE1 1024

// ---------------- bulk mfma scan: 128 tok x 2048 codes per block ----------------
// R6 structure (proven 504 us): 512 threads / 8 waves, depth-2 reg prefetch,
// T4 barrier (lgkmcnt-only, vmcnt never drained). New this round:
//  (1) pseudo-random per-block start skew (s_sleep) to break the inter-block
//      phase-lock that serializes MFMA and VALU bursts;
//  (2) T5 setprio(1) around the MFMA cluster so de-phased MFMA-burst waves
//      pre-empt staging waves.
__global__ __launch_bounds__(512, 4) void bulk_kernel(
    const float* __restrict__ zf, const short* __restrict__ zhi,
    const short* __restrict__ ehi, const short* __restrict__ elo,
    const float* __restrict__ e2h,
    float* __restrict__ m1a, float* __restrict__ m2a, int* __restrict__ i1a)
{
    __shared__ __align__(16) short smem[2][16384];   // 2 x 32 KB
    __shared__ float e2sall[SPLITK];                 // 2048 floats = 8 KB
    __shared__ float s1m[BTOK], s2m[BTOK];
    __shared__ int   i1m[BTOK];

    // de-phase: per-block random start skew, 0..15 x ~512 cyc (uniform in block)
    {
        int d = (int)((blockIdx.x * 2654435761u) >> 28);
        for (int i = 0; i < d; ++i) __builtin_amdgcn_s_sleep(8);
    }

    const int tid  = threadIdx.x;
    const int lane = tid & 63;
    const int w    = tid >> 6;          // 0..7
    const int wt   = w & 1;             // token 64-half
    const int wc   = w >> 1;            // code 32-tile (0..3)
    const int g     = blockIdx.x & 255;
    const int split = blockIdx.x >> 8;
    const int tok0  = g * BTOK;
    const int cs0   = split * SPLITK;

    // staging: ONE e-slot and ONE z-slot per thread (512 slots = 128 rows x 4 q)
    const int r0 = tid >> 2, q0 = tid & 3;
    const int so0 = r0 * 32 + ((q0 ^ ((r0 >> 1) & 3)) << 3);

    // mfma read addressing (shorts), XOR-swizzled granules
    const int l31 = lane & 31, hh = lane >> 5;
    const int swz = (l31 >> 1) & 3;
    const int arow = (wc * 32 + l31) * 32;      // 32-code tile
    const int brow = (wt * 64 + l31) * 32;      // token half; +TILE1 = +32 rows
    const int a0 = arow + ((hh ^ swz) << 3);
    const int a1 = arow + (((2 + hh) ^ swz) << 3);
    const int b0 = brow + ((hh ^ swz) << 3);
    const int b1 = brow + (((2 + hh) ^ swz) << 3);

    float m1[2] = {-FLT_MAX, -FLT_MAX}, m2[2] = {-FLT_MAX, -FLT_MAX};
    int   k1[2] = {0x7fffffff, 0x7fffffff};

    // depth-2 prefetch register slots (static names — rule #20)
    bf16x8 ehA, elA, zhA;  float4 zfaA, zfbA;
    bf16x8 ehB, elB, zhB;  float4 zfaB, zfbB;

    f32x16 acc[2];
    #pragma unroll
    for (int j = 0; j < 2; j++)
        #pragma unroll
        for (int r = 0; r < 16; r++) acc[j][r] = 0.f;

    const int NST = (SPLITK / CHUNK) * 8;   // 128 flat stages (16 chunks x 8)

    auto ISSUE_A = [&](int s) {
        const int code0 = cs0 + (s >> 3) * CHUNK;
        const int d0 = (s & 7) * 32;
        const size_t ei = ((size_t)(code0 + r0) << 8) + d0 + (q0 << 3);
        const size_t zi = ((size_t)(tok0 + r0) << 8) + d0 + (q0 << 3);
        ehA = *(const bf16x8*)(ehi + ei);
        elA = *(const bf16x8*)(elo + ei);
        zhA = *(const bf16x8*)(zhi + zi);
        zfaA = *(const float4*)(zf + zi);
        zfbA = *(const float4*)(zf + zi + 4);
    };
    auto ISSUE_B = [&](int s) {
        const int code0 = cs0 + (s >> 3) * CHUNK;
        const int d0 = (s & 7) * 32;
        const size_t ei = ((size_t)(code0 + r0) << 8) + d0 + (q0 << 3);
        const size_t zi = ((size_t)(tok0 + r0) << 8) + d0 + (q0 << 3);
        ehB = *(const bf16x8*)(ehi + ei);
        elB = *(const bf16x8*)(elo + ei);
        zhB = *(const bf16x8*)(zhi + zi);
        zfaB = *(const float4*)(zf + zi);
        zfbB = *(const float4*)(zf + zi + 4);
    };

    auto STORE_A = [&](int buf) {
        bf16x8 zl0 = lo8(zhA, zfaA, zfbA);
        short* sm = smem[buf];
        *(bf16x8*)(sm + B_ESH + so0) = ehA;
        *(bf16x8*)(sm + B_ESL + so0) = elA;
        *(bf16x8*)(sm + B_ZSH + so0) = zhA;
        *(bf16x8*)(sm + B_ZSL + so0) = zl0;
    };
    auto STORE_B = [&](int buf) {
        bf16x8 zl0 = lo8(zhB, zfaB, zfbB);
        short* sm = smem[buf];
        *(bf16x8*)(sm + B_ESH + so0) = ehB;
        *(bf16x8*)(sm + B_ESL + so0) = elB;
        *(bf16x8*)(sm + B_ZSH + so0) = zhB;
        *(bf16x8*)(sm + B_ZSL + so0) = zl0;
    };

    // prologue: e2 table (whole split), stages 0 (A) and 1 (B) in flight,
    // stage 0 into buffer 0. Full __syncthreads here is fine (once).
    #pragma unroll
    for (int i = 0; i < SPLITK / 512; i++) {
        int idx = tid + i * 512;
        e2sall[idx] = e2h[cs0 + idx];
    }
    ISSUE_A(0);
    ISSUE_B(1);
    STORE_A(0);
    __syncthreads();

    #pragma unroll 2
    for (int s = 0; s < NST; s++) {
        const int cur = s & 1;
        if (s + 2 < NST) {                 // refill the slot consumed last iter
            if (cur == 0) ISSUE_A(s + 2); else ISSUE_B(s + 2);
        }
        {
            const short* sm = smem[cur];
            __builtin_amdgcn_s_setprio(1);
            {   // kstep 0
                bf16x8 ah  = *(const bf16x8*)(sm + B_ESH + a0);
                bf16x8 al  = *(const bf16x8*)(sm + B_ESL + a0);
                bf16x8 b0h = *(const bf16x8*)(sm + B_ZSH + b0);
                bf16x8 b0l = *(const bf16x8*)(sm + B_ZSL + b0);
                bf16x8 b1h = *(const bf16x8*)(sm + B_ZSH + TILE1 + b0);
                bf16x8 b1l = *(const bf16x8*)(sm + B_ZSL + TILE1 + b0);
                MFMA3(acc[0], ah, al, b0h, b0l);
                MFMA3(acc[1], ah, al, b1h, b1l);
            }
            {   // kstep 1
                bf16x8 ah  = *(const bf16x8*)(sm + B_ESH + a1);
                bf16x8 al  = *(const bf16x8*)(sm + B_ESL + a1);
                bf16x8 b0h = *(const bf16x8*)(sm + B_ZSH + b1);
                bf16x8 b0l = *(const bf16x8*)(sm + B_ZSL + b1);
                bf16x8 b1h = *(const bf16x8*)(sm + B_ZSH + TILE1 + b1);
                bf16x8 b1l = *(const bf16x8*)(sm + B_ZSL + TILE1 + b1);
                MFMA3(acc[0], ah, al, b0h, b0l);
                MFMA3(acc[1], ah, al, b1h, b1l);
            }
            __builtin_amdgcn_s_setprio(0);
        }
        if ((s & 7) == 7) {
            // epilogue for chunk c = s>>3: a = acc - e2/2, top-2 insert, re-zero acc
            const int code0 = cs0 + (s >> 3) * CHUNK;
            const float* e2c = e2sall + (s >> 3) * CHUNK;
            float ev[16];
            #pragma unroll
            for (int r = 0; r < 16; r++)
                ev[r] = e2c[wc * 32 + hh * 4 + (r & 3) + ((r >> 2) << 3)];
            #pragma unroll
            for (int tt = 0; tt < 2; tt++) {
                #pragma unroll
                for (int r = 0; r < 16; r++) {
                    float a = acc[tt][r] - ev[r];
                    int code = code0 + wc * 32 + hh * 4 + (r & 3) + ((r >> 2) << 3);
                    if (a > m1[tt]) { m2[tt] = m1[tt]; m1[tt] = a; k1[tt] = code; }
                    else if (a > m2[tt]) m2[tt] = a;
                }
            }
            #pragma unroll
            for (int j = 0; j < 2; j++)
                #pragma unroll
                for (int r = 0; r < 16; r++) acc[j][r] = 0.f;
        }
        if (s + 1 < NST) {                 // store stage s+1 (loads issued iter s-1)
            if (cur == 0) STORE_B(cur ^ 1); else STORE_A(cur ^ 1);
        }
        // T4 barrier: LDS-write visibility only; vmcnt NOT drained — the s+2
        // prefetch loads stay in flight across the barrier. sched_barrier(0)
        // fences next-iteration ds_reads from hoisting above (rule #18).
        asm volatile("s_waitcnt lgkmcnt(0)" ::: "memory");
        __builtin_amdgcn_s_barrier();
        __builtin_amdgcn_sched_barrier(0);
    }

    // merge lane halves (hh=0 vs hh=1: same token column, different code rows)
    #pragma unroll
    for (int tt = 0; tt < 2; tt++) {
        float o1 = __shfl_xor(m1[tt], 32);
        float o2 = __shfl_xor(m2[tt], 32);
        int   oi = __shfl_xor(k1[tt], 32);
        bool take = (o1 > m1[tt]) || (o1 == m1[tt] && oi < k1[tt]);
        float w1 = take ? o1 : m1[tt];
        int   wi = take ? oi : k1[tt];
        float ls = take ? m1[tt] : o1;
        m2[tt] = fmaxf(fmaxf(m2[tt], o2), ls);
        m1[tt] = w1; k1[tt] = wi;
    }
    // cross-wave merge: waves wc=0..3 share tokens (wt fixed per wave)
    __syncthreads();
    if (wc == 0 && lane < 32) {
        #pragma unroll
        for (int tt = 0; tt < 2; tt++) {
            int tl = wt * 64 + tt * 32 + lane;
            s1m[tl] = m1[tt]; s2m[tl] = m2[tt]; i1m[tl] = k1[tt];
        }
    }
    __syncthreads();
    #pragma unroll
    for (int mw = 1; mw < 3; mw++) {
        if (wc == mw && lane < 32) {
            #pragma unroll
            for (int tt = 0; tt < 2; tt++) {
                int tl = wt * 64 + tt * 32 + lane;
                float a1 = s1m[tl], a2 = s2m[tl]; int ai = i1m[tl];
                bool take = (a1 > m1[tt]) || (a1 == m1[tt] && ai < k1[tt]);
                float w1 = take ? a1 : m1[tt];
                int   wi = take ? ai : k1[tt];
                float ls = take ? m1[tt] : a1;
                float w2 = fmaxf(fmaxf(m2[tt], a2), ls);
                s1m[tl] = w1; s2m[tl] = w2; i1m[tl] = wi;
            }
        }
        __syncthreads();
    }
    if (wc == 3 && lane < 32) {
        #pragma unroll
        for (int tt = 0; tt < 2; tt++) {
            int tl = wt * 64 + tt * 32 + lane;
            float a1 = s1m[tl], a2 = s2m[tl]; int ai = i1m[tl];
            bool take = (a1 > m1[tt]) || (a1 == m1[tt] && ai < k1[tt]);
            float w1 = take ? a1 : m1[tt];
            int   wi = take ? ai : k1[tt];
            float ls = take ? m1[tt] : a1;
            float w2 = fmaxf(fmaxf(m2[tt], a2), ls);
            size_t t = (size_t)(tok0 + tl) * NSPLIT + split;
            m1a[t] = w1; m2a[t] = w2; i1a[t] = wi;
        }
    }
}

// ---------------- merge splits, detect contested, zero cand counters ----------------
__global__ __launch_bounds__(256) void merge_kernel(
    const float* __restrict__ m1a, const float* __restrict__ m2a,
    const int* __restrict__ i1a, float* __restrict__ m1f,
    int* __restrict__ idxf, int* __restrict__ clist,
    unsigned* __restrict__ ccount, unsigned* __restrict__ ccnt_g)
{
    int t = blockIdx.x * 256 + threadIdx.x;
    ccnt_g[t] = 0u;
    float w1 = m1a[t * NSPLIT], w2 = m2a[t * NSPLIT];
    int   wi = i1a[t * NSPLIT];
    #pragma unroll
    for (int s = 1; s < NSPLIT; s++) {
        float a1 = m1a[t * NSPLIT + s], a2 = m2a[t * NSPLIT + s];
        int   ai = i1a[t * NSPLIT + s];
        bool take = (a1 > w1) || (a1 == w1 && ai < wi);
        float n1 = take ? a1 : w1;
        int   ni = take ? ai : wi;
        float ls = take ? w1 : a1;
        w2 = fmaxf(fmaxf(w2, a2), ls);
        w1 = n1; wi = ni;
    }
    idxf[t] = wi; m1f[t] = w1;
    if (w1 - w2 < CTAU_M) {
        unsigned p = atomicAdd(ccount, 1u);
        clist[p] = t;
    }
}

// LDS short-offsets (rescue): ESH=0 ESL=4096 ZSH=8192 ZSL=9216
#define R_ESH 0
#define R_ESL 4096
#define R_ZSH 8192
#define R_ZSL 9216

// ---------------- rescue: parallel mfma candidate sweep (32 tok x 1024 codes) ----------------
__global__ __launch_bounds__(256) void rescue_kernel(
    const float* __restrict__ zf, const short* __restrict__ zhi,
    const short* __restrict__ ehi, const short* __restrict__ elo,
    const float* __restrict__ e2h, const float* __restrict__ m1f,
    const unsigned* __restrict__ ccount, const int* __restrict__ clist,
    unsigned* __restrict__ ccnt_g, int* __restrict__ cand_g)
{
    const unsigned count = *ccount;
    const unsigned base  = blockIdx.x * RBTOK;
    if (base >= count) return;
    const int nt = min(RBTOK, (int)(count - base));
    const int sp = blockIdx.y;

    __shared__ __align__(16) short rsm[10240];   // 20 KB
    __shared__ int   tls[RBTOK];
    __shared__ float thr[RBTOK];
    __shared__ float e2s[CHUNK];

    const int tid  = threadIdx.x;
    const int lane = tid & 63;
    const int w    = tid >> 6;

    if (tid < RBTOK) {
        int s = (tid < nt) ? tid : (nt - 1);
        int t = clist[base + s];
        tls[tid] = t;
        thr[tid] = (tid < nt) ? (m1f[t] - CAND_MM) : FLT_MAX;
    }
    __syncthreads();

    const int l31 = lane & 31, hh = lane >> 5;
    const float mythr = thr[l31];
    const int   mytok = tls[l31];
    const int swz = (l31 >> 1) & 3;
    const int arow = (w * 32 + l31) * 32;
    const int brow = l31 * 32;
    const int a0 = arow + ((hh ^ swz) << 3);
    const int a1 = arow + (((2 + hh) ^ swz) << 3);
    const int b0 = brow + ((hh ^ swz) << 3);
    const int b1 = brow + (((2 + hh) ^ swz) << 3);

    // e staging: 2 slots/thread (pure copies); z: tid<128, one slot each (hi+lo)
    const int er0 = tid >> 2, eq0 = tid & 3;
    const int er1 = er0 + 64;
    const int eso0 = er0 * 32 + ((eq0 ^ ((er0 >> 1) & 3)) << 3);
    const int eso1 = er1 * 32 + ((eq0 ^ ((er1 >> 1) & 3)) << 3);
    const int zr = (tid & 127) >> 2, zq = tid & 3;
    const int zso = zr * 32 + ((zq ^ ((zr >> 1) & 3)) << 3);

    for (int c = 0; c < RSPLIT / CHUNK; c++) {
        const int code0 = sp * RSPLIT + c * CHUNK;
        const float e2v = (tid < CHUNK) ? e2h[code0 + tid] : 0.f;
        f32x16 acc;
        #pragma unroll
        for (int r = 0; r < 16; r++) acc[r] = 0.f;

        for (int st = 0; st < 8; st++) {
            const int d0 = st * 32;
            const size_t ei0 = ((size_t)(code0 + er0) << 8) + d0 + (eq0 << 3);
            const size_t ei1 = ((size_t)(code0 + er1) << 8) + d0 + (eq0 << 3);
            bf16x8 eh0 = *(const bf16x8*)(ehi + ei0);
            bf16x8 el0 = *(const bf16x8*)(elo + ei0);
            bf16x8 eh1 = *(const bf16x8*)(ehi + ei1);
            bf16x8 el1 = *(const bf16x8*)(elo + ei1);
            bf16x8 zh = {}, zl = {};
            if (tid < 128) {
                const size_t zi = ((size_t)tls[zr] << 8) + d0 + (zq << 3);
                zh = *(const bf16x8*)(zhi + zi);
                float4 za = *(const float4*)(zf + zi);
                float4 zb = *(const float4*)(zf + zi + 4);
                zl = lo8(zh, za, zb);
            }
            __syncthreads();
            *(bf16x8*)(rsm + R_ESH + eso0) = eh0;
            *(bf16x8*)(rsm + R_ESL + eso0) = el0;
            *(bf16x8*)(rsm + R_ESH + eso1) = eh1;
            *(bf16x8*)(rsm + R_ESL + eso1) = el1;
            if (tid < 128) {
                *(bf16x8*)(rsm + R_ZSH + zso) = zh;
                *(bf16x8*)(rsm + R_ZSL + zso) = zl;
            }
            if (st == 0 && tid < CHUNK) e2s[tid] = e2v;
            __syncthreads();
            {
                bf16x8 ah = *(const bf16x8*)(rsm + R_ESH + a0);
                bf16x8 al = *(const bf16x8*)(rsm + R_ESL + a0);
                bf16x8 bh = *(const bf16x8*)(rsm + R_ZSH + b0);
                bf16x8 bl = *(const bf16x8*)(rsm + R_ZSL + b0);
                MFMA3(acc, ah, al, bh, bl);
            }
            {
                bf16x8 ah = *(const bf16x8*)(rsm + R_ESH + a1);
                bf16x8 al = *(const bf16x8*)(rsm + R_ESL + a1);
                bf16x8 bh = *(const bf16x8*)(rsm + R_ZSH + b1);
                bf16x8 bl = *(const bf16x8*)(rsm + R_ZSL + b1);
                MFMA3(acc, ah, al, bh, bl);
            }
        }
        #pragma unroll
        for (int r = 0; r < 16; r++) {
            const int local = w * 32 + hh * 4 + (r & 3) + ((r >> 2) << 3);
            float a = acc[r] - e2s[local];
            if (a >= mythr) {
                unsigned p = atomicAdd(&ccnt_g[mytok], 1u);
                if (p < MAXCAND) cand_g[(size_t)mytok * MAXCAND + p] = code0 + local;
            }
        }
    }
}

// ---------------- resolve: np-exact d over candidates, first-index min ----------------
__global__ __launch_bounds__(256) void resolve_kernel(
    const float* __restrict__ z, const float* __restrict__ emb,
    const float* __restrict__ e2np, const float* __restrict__ Cnp,
    const unsigned* __restrict__ ccount, const int* __restrict__ clist,
    const unsigned* __restrict__ ccnt_g, const int* __restrict__ cand_g,
    int* __restrict__ idxf)
{
    const unsigned count = *ccount;
    const int lane = threadIdx.x & 63;
    const int w    = threadIdx.x >> 6;
    for (unsigned c = blockIdx.x * 4 + w; c < count; c += gridDim.x * 4) {
        const int t = clist[c];
        const int n = (int)min(ccnt_g[t], (unsigned)MAXCAND);
        float bd = FLT_MAX; int bk = 0x7fffffff;
        if (lane < n) {
            const int k = cand_g[(size_t)t * MAXCAND + lane];
            float g = np_einsum256(z + (size_t)t * D_DIM, emb + (size_t)k * D_DIM);
            bd = np_dtilde(Cnp[t], e2np[k], g);
            bk = k;
        }
        #pragma unroll
        for (int off = 32; off >= 1; off >>= 1) {
            float od = __shfl_xor(bd, off);
            int   ok = __shfl_xor(bk, off);
            if (od < bd || (od == bd && ok < bk)) { bd = od; bk = ok; }
        }
        if (lane == 0 && n > 0) idxf[t] = bk;
    }
}

// ---------------- gather z_q, write out0, fp64 MSE sum ----------------
__global__ __launch_bounds__(256) void out_loss_kernel(
    const float* __restrict__ z, const float* __restrict__ emb,
    const int* __restrict__ idxf, float* __restrict__ out0,
    double* __restrict__ loss_sum)
{
    const int total4 = N_TOK * (D_DIM / 4);
    double lsum = 0.0;
    for (int p = blockIdx.x * 256 + threadIdx.x; p < total4; p += gridDim.x * 256) {
        const int n  = p >> 6;
        const int d4 = p & 63;
        const int k  = idxf[n];
        float4 zv = ((const float4*)z)[p];
        float4 ev = ((const float4*)(emb + (size_t)k * D_DIM))[d4];
        float dx = ev.x - zv.x, dy = ev.y - zv.y,
              dz = ev.z - zv.z, dw = ev.w - zv.w;
        float4 o;
        o.x = zv.x + dx; o.y = zv.y + dy; o.z = zv.z + dz; o.w = zv.w + dw;
        ((float4*)out0)[p] = o;
        lsum += (double)dx * dx + (double)dy * dy
              + (double)dz * dz + (double)dw * dw;
    }
    #pragma unroll
    for (int off = 32; off >= 1; off >>= 1) lsum += __shfl_xor(lsum, off);
    __shared__ double wsum[4];
    const int wv = threadIdx.x >> 6;
    if ((threadIdx.x & 63) == 0) wsum[wv] = lsum;
    __syncthreads();
    if (threadIdx.x == 0)
        atomicAdd(loss_sum, wsum[0] + wsum[1] + wsum[2] + wsum[3]);
}

__global__ __launch_bounds__(256) void finalize_kernel(
    const int* __restrict__ idxf, const double* __restrict__ loss_sum,
    float* __restrict__ out)
{
    const int t = blockIdx.x * 256 + threadIdx.x;
    if (t < N_TOK) out[8388611 + t] = (float)idxf[t];
    if (t == 0) {
        double mse = *loss_sum * (1.0 / 8388608.0);
        out[8388608] = (float)(1.25 * mse);
        out[8388609] = (float)(0.25 * mse);
        out[8388610] = (float)mse;
    }
}

extern "C" void kernel_launch(void* const* d_in, const int* in_sizes, int n_in,
                              void* d_out, int out_size, void* d_ws, size_t ws_size,
                              hipStream_t stream)
{
    const float* z   = (const float*)d_in[0];
    const float* emb = (const float*)d_in[1];
    float* out = (float*)d_out;
    char*  ws  = (char*)d_ws;
    char*  ob  = (char*)d_out;

    // big scratch inside d_out (all reads finish before out_loss/finalize rewrite it)
    short*    ehi    = (short*)(ob + 0);
    short*    elo    = (short*)(ob + 4194304);
    short*    zhi    = (short*)(ob + 8388608);
    float*    m1a    = (float*)(ob + 25165824);
    float*    m2a    = (float*)(ob + 25690112);
    int*      i1a    = (int*)(ob + 26214400);
    int*      cand_g = (int*)(ob + 26738688);

    double*   loss_sum = (double*)(ws + 0);
    unsigned* ccount   = (unsigned*)(ws + 8);
    float*    e2np     = (float*)(ws + 16);
    float*    e2h      = (float*)(ws + 32784);
    float*    Cnp      = (float*)(ws + 65552);
    float*    m1f      = (float*)(ws + 196624);
    int*      idxf     = (int*)(ws + 327696);
    int*      clist    = (int*)(ws + 458768);
    unsigned* ccnt_g   = (unsigned*)(ws + 589840);

    prep_e_kernel<<<dim3(K_CODES / 256), dim3(256), 0, stream>>>(
        emb, e2np, e2h, ccount, loss_sum);
    prep_z_kernel<<<dim3(N_TOK / 256), dim3(256), 0, stream>>>(z, Cnp);
    cvt_e_kernel<<<dim3(K_CODES * D_DIM / 8 / 256), dim3(256), 0, stream>>>(emb, ehi, elo);
    cvt_zhi_kernel<<<dim3(N_TOK * D_DIM / 8 / 256), dim3(256), 0, stream>>>(z, zhi);
    bulk_kernel<<<dim3((N_TOK / BTOK) * NSPLIT), dim3(512), 0, stream>>>(
        z, zhi, ehi, elo, e2h, m1a, m2a, i1a);
    merge_kernel<<<dim3(N_TOK / 256), dim3(256), 0, stream>>>(
        m1a, m2a, i1a, m1f, idxf, clist, ccount, ccnt_g);
    rescue_kernel<<<dim3(N_TOK / RBTOK, NRS), dim3(256), 0, stream>>>(
        z, zhi, ehi, elo, e2h, m1f, ccount, clist, ccnt_g, cand_g);
    resolve_kernel<<<dim3(128), dim3(256), 0, stream>>>(
        z, emb, e2np, Cnp, ccount, clist, ccnt_g, cand_g, idxf);
    out_loss_kernel<<<dim3(1024), dim3(256), 0, stream>>>(
        z, emb, idxf, out, loss_sum);
    finalize_kernel<<<dim3(N_TOK / 256), dim3(256), 0, stream>>>(
        idxf, loss_sum, out);
}

// Round 9
// 767.006 us; speedup vs baseline: 1.2084x; 1.0675x over previous
//
#include <hip/hip_runtime.h>
#include <hip/hip_bf16.h>
#include <cfloat>

#define N_TOK   32768
#define K_CODES 8192
#define D_DIM   256
#define BTOK    128        // tokens per bulk block
#define CHUNK   128        // codes per chunk
#define NSPLIT  4          // code-range splits in bulk
#define SPLITK  (K_CODES / NSPLIT)
#define CTAU_M  3.0e-5f    // contested if (m1-m2) < this (acc units)
#define CAND_MM 2.4e-5f    // rescue candidate window (acc units)
#define MAXCAND 16
#define RBTOK   32         // tokens per rescue block
#define NRS     8          // code splits in rescue
#define RSPLIT  (K_CODES / NRS)

typedef __attribute__((ext_vector_type(4)))  short bf16x4;
typedef __attribute__((ext_vector_type(8)))  short bf16x8;
typedef __attribute__((ext_vector_type(16))) float f32x16;

// ws layout (bytes) — 720,912 B total (unchanged):
//   0      double loss_sum ; 8 uint ccount (+pad)
//   16     float e2np[8192]
//   32784  float e2h[8192]      0.5*e2np
//   65552  float Cnp[32768]
//   196624 float m1f[32768]
//   327696 int   idxf[32768]
//   458768 int   clist[32768]
//   589840 uint  ccnt_g[32768]   -> end 720912
//
// d_out scratch (33,685,516 B buffer; fully rewritten by out_loss/finalize after
// all scratch reads complete — stream-ordered). zhi scratch REMOVED (zh is
// recomputed from zf in-kernel); e gains a fragment-ordered transposed copy:
//   0         short ehi[8192*256]   (4,194,304)  linear, rescue path
//   4194304   short elo[8192*256]   (4,194,304)  linear, rescue path
//   8388608   short eht[16][8192][16] (4,194,304) transposed, bulk A-frags
//   12582912  short elt[16][8192][16] (4,194,304)
//   16777216  float m1a[32768*4]    (524,288)
//   17301504  float m2a[32768*4]    (524,288)
//   17825792  int   i1a[32768*4]    (524,288)
//   18350080  int   cand_g[32768*16](2,097,152) -> end 20,447,232 < 33,685,516

// ======== numpy bit-exact fp32 emulation (NO fma contraction) ========
__device__ __forceinline__ float np_sumsq256(const float* __restrict__ row) {
    #pragma clang fp contract(off)
    float blk[2];
    #pragma unroll
    for (int b = 0; b < 2; b++) {
        const float* x = row + b * 128;
        float r[8];
        #pragma unroll
        for (int j = 0; j < 8; j++) { float v = x[j]; r[j] = v * v; }
        for (int i = 8; i < 128; i += 8) {
            #pragma unroll
            for (int j = 0; j < 8; j++) { float v = x[i + j]; r[j] += v * v; }
        }
        blk[b] = ((r[0] + r[1]) + (r[2] + r[3])) + ((r[4] + r[5]) + (r[6] + r[7]));
    }
    return blk[0] + blk[1];
}

__device__ __forceinline__ float np_einsum256(const float* __restrict__ a,
                                              const float* __restrict__ b) {
    #pragma clang fp contract(off)
    float A0 = 0.f, A1 = 0.f, A2 = 0.f, A3 = 0.f;
    for (int m = 0; m < 256; m += 16) {
        A0 = a[m+ 0]*b[m+ 0] + (a[m+ 4]*b[m+ 4] + (a[m+ 8]*b[m+ 8] + (a[m+12]*b[m+12] + A0)));
        A1 = a[m+ 1]*b[m+ 1] + (a[m+ 5]*b[m+ 5] + (a[m+ 9]*b[m+ 9] + (a[m+13]*b[m+13] + A1)));
        A2 = a[m+ 2]*b[m+ 2] + (a[m+ 6]*b[m+ 6] + (a[m+10]*b[m+10] + (a[m+14]*b[m+14] + A2)));
        A3 = a[m+ 3]*b[m+ 3] + (a[m+ 7]*b[m+ 7] + (a[m+11]*b[m+11] + (a[m+15]*b[m+15] + A3)));
    }
    return (A0 + A1) + (A2 + A3);
}

__device__ __forceinline__ float np_dtilde(float Cn, float e2k, float g) {
    #pragma clang fp contract(off)
    float t = Cn + e2k;
    float d = t - 2.0f * g;
    return d;
}

// ======== bf16 split helpers ========
__device__ __forceinline__ unsigned short bf16_rne(float f) {
    unsigned u = __float_as_uint(f);
    unsigned r = u + 0x7fffu + ((u >> 16) & 1u);
    return (unsigned short)(r >> 16);
}
__device__ __forceinline__ void split_bf16(float f, short& hi, short& lo) {
    unsigned short h = bf16_rne(f);
    hi = (short)h;
    float hf = __uint_as_float(((unsigned)h) << 16);
    lo = (short)bf16_rne(f - hf);
}
// full hi+lo split from fp32 source via v_cvt_pk_bf16_f32 (RNE, bit-identical
// to bf16_rne for finite normals). Shared by bulk + rescue so approx scores
// stay mutually bit-consistent. Replaces the old zhi-scratch load + lo8.
__device__ __forceinline__ void split8v(float4 a, float4 b, bf16x8& h, bf16x8& l) {
    float f[8] = {a.x, a.y, a.z, a.w, b.x, b.y, b.z, b.w};
    #pragma unroll
    for (int i = 0; i < 8; i += 2) {
        __hip_bfloat162 hp = __float22bfloat162_rn(make_float2(f[i], f[i + 1]));
        unsigned hu; __builtin_memcpy(&hu, &hp, 4);
        h[i]     = (short)(hu & 0xffffu);
        h[i + 1] = (short)(hu >> 16);
        float h0 = __uint_as_float(hu << 16);
        float h1 = __uint_as_float(hu & 0xffff0000u);
        __hip_bfloat162 lp = __float22bfloat162_rn(make_float2(f[i] - h0, f[i + 1] - h1));
        unsigned lu; __builtin_memcpy(&lu, &lp, 4);
        l[i]     = (short)(lu & 0xffffu);
        l[i + 1] = (short)(lu >> 16);
    }
}

#define MFMA3(A, ah, al, bh, bl) \
    A = __builtin_amdgcn_mfma_f32_32x32x16_bf16(ah, bh, A, 0, 0, 0); \
    A = __builtin_amdgcn_mfma_f32_32x32x16_bf16(ah, bl, A, 0, 0, 0); \
    A = __builtin_amdgcn_mfma_f32_32x32x16_bf16(al, bh, A, 0, 0, 0);

// ---------------- prep kernels ----------------
__global__ __launch_bounds__(256) void prep_e_kernel(
    const float* __restrict__ emb, float* __restrict__ e2np,
    float* __restrict__ e2h, unsigned* __restrict__ ccount,
    double* __restrict__ loss_sum)
{
    int k = blockIdx.x * 256 + threadIdx.x;
    float v = np_sumsq256(emb + (size_t)k * D_DIM);
    e2np[k] = v;
    e2h[k]  = 0.5f * v;
    if (k == 0) { *ccount = 0u; *loss_sum = 0.0; }
}

__global__ __launch_bounds__(256) void prep_z_kernel(
    const float* __restrict__ z, float* __restrict__ Cnp)
{
    int t = blockIdx.x * 256 + threadIdx.x;
    Cnp[t] = np_sumsq256(z + (size_t)t * D_DIM);
}

// ---------------- one-time conversion into d_out scratch ----------------
// writes linear hi/lo (rescue) AND fragment-ordered transposed hi/lo (bulk):
// et[d16][code][16 shorts], d16 = d/16 — a wave's A-fragment load is a fully
// contiguous 1KB line.
__global__ __launch_bounds__(256) void cvt_e_kernel(
    const float* __restrict__ src, short* __restrict__ hi, short* __restrict__ lo,
    short* __restrict__ hit, short* __restrict__ lot)
{
    size_t p = ((size_t)blockIdx.x * 256 + threadIdx.x) * 8;
    float4 v0 = *(const float4*)(src + p);
    float4 v1 = *(const float4*)(src + p + 4);
    short h[8], l[8];
    split_bf16(v0.x, h[0], l[0]); split_bf16(v0.y, h[1], l[1]);
    split_bf16(v0.z, h[2], l[2]); split_bf16(v0.w, h[3], l[3]);
    split_bf16(v1.x, h[4], l[4]); split_bf16(v1.y, h[5], l[5]);
    split_bf16(v1.z, h[6], l[6]); split_bf16(v1.w, h[7], l[7]);
    bf16x8 vh = {h[0],h[1],h[2],h[3],h[4],h[5],h[6],h[7]};
    bf16x8 vl = {l[0],l[1],l[2],l[3],l[4],l[5],l[6],l[7]};
    *(bf16x8*)(hi + p) = vh;
    *(bf16x8*)(lo + p) = vl;
    const int code = (int)(p >> 8);
    const int d    = (int)(p & 255);
    size_t tp = ((size_t)(d >> 4) * K_CODES + code) * 16 + (d & 15);
    *(bf16x8*)(hit + tp) = vh;
    *(bf16x8*)(lot + tp) = vl;
}

// LDS short-offsets (bulk): z only. ZSH=0 ZSL=4096 within an 8192-short buffer;
// row stride 32 shorts; +TILE1 = +32 rows.
#define Z_SH 0
#define Z_SL 4096
#define TILE1 1024

// ---------------- bulk mfma scan: 128 tok x 2048 codes per block ----------------
// 512 threads / 8 waves. A-operand (e) comes DIRECTLY from global/L2 via the
// fragment-ordered transposed copy (coalesced 1KB/wave loads, depth-1 prefetch
// into parity-named register sets) — e never touches LDS. LDS holds only the
// z tile (16KB buffer, double-buffered, depth-2 reg prefetch of zf). zh/zl are
// computed in-reg from zf (split8v; zhi scratch eliminated). T4 barrier:
// lgkmcnt-only + raw s_barrier, vmcnt never drained. T5 setprio around MFMAs.
__global__ __launch_bounds__(512, 4) void bulk_kernel(
    const float* __restrict__ zf, const short* __restrict__ eht,
    const short* __restrict__ elt, const float* __restrict__ e2h,
    float* __restrict__ m1a, float* __restrict__ m2a, int* __restrict__ i1a)
{
    __shared__ __align__(16) short smem[2][8192];    // 2 x 16 KB (z hi+lo)
    __shared__ float e2sall[SPLITK];                 // 8 KB
    __shared__ float s1m[BTOK], s2m[BTOK];
    __shared__ int   i1m[BTOK];

    const int tid  = threadIdx.x;
    const int lane = tid & 63;
    const int w    = tid >> 6;          // 0..7
    const int wt   = w & 1;             // token 64-half
    const int wc   = w >> 1;            // code 32-tile (0..3)
    const int g     = blockIdx.x & 255;
    const int split = blockIdx.x >> 8;
    const int tok0  = g * BTOK;
    const int cs0   = split * SPLITK;

    // z staging: ONE slot per thread (512 slots = 128 rows x 4 granules)
    const int r0 = tid >> 2, q0 = tid & 3;
    const int so0 = r0 * 32 + ((q0 ^ ((r0 >> 1) & 3)) << 3);

    // mfma addressing
    const int l31 = lane & 31, hh = lane >> 5;
    const int swz = (l31 >> 1) & 3;
    const int acode = cs0 + wc * 32 + l31;           // absolute code row (chunk adds c*CHUNK)
    const int brow = (wt * 64 + l31) * 32;
    const int b0 = brow + ((hh ^ swz) << 3);
    const int b1 = brow + (((2 + hh) ^ swz) << 3);

    float m1[2] = {-FLT_MAX, -FLT_MAX}, m2[2] = {-FLT_MAX, -FLT_MAX};
    int   k1[2] = {0x7fffffff, 0x7fffffff};

    // prefetch register slots (static names — rule #20)
    float4 zfaA, zfbA, zfaB, zfbB;                       // z depth-2
    bf16x8 a0hA, a0lA, a1hA, a1lA;                       // A-frags, stage-parity A
    bf16x8 a0hB, a0lB, a1hB, a1lB;                       // A-frags, stage-parity B

    f32x16 acc[2];
    #pragma unroll
    for (int j = 0; j < 2; j++)
        #pragma unroll
        for (int r = 0; r < 16; r++) acc[j][r] = 0.f;

    const int NST = (SPLITK / CHUNK) * 8;   // 128 flat stages (16 chunks x 8)

    auto ZISSUE_A = [&](int s) {
        const size_t zi = ((size_t)(tok0 + r0) << 8) + (s & 7) * 32 + (q0 << 3);
        zfaA = *(const float4*)(zf + zi);
        zfbA = *(const float4*)(zf + zi + 4);
    };
    auto ZISSUE_B = [&](int s) {
        const size_t zi = ((size_t)(tok0 + r0) << 8) + (s & 7) * 32 + (q0 << 3);
        zfaB = *(const float4*)(zf + zi);
        zfbB = *(const float4*)(zf + zi + 4);
    };
    auto AISSUE_A = [&](int s) {
        const int c = s >> 3, dst = s & 7;
        const size_t p0 = ((size_t)(2 * dst + 0) * K_CODES + (acode + c * CHUNK)) * 16 + hh * 8;
        const size_t p1 = ((size_t)(2 * dst + 1) * K_CODES + (acode + c * CHUNK)) * 16 + hh * 8;
        a0hA = *(const bf16x8*)(eht + p0);
        a0lA = *(const bf16x8*)(elt + p0);
        a1hA = *(const bf16x8*)(eht + p1);
        a1lA = *(const bf16x8*)(elt + p1);
    };
    auto AISSUE_B = [&](int s) {
        const int c = s >> 3, dst = s & 7;
        const size_t p0 = ((size_t)(2 * dst + 0) * K_CODES + (acode + c * CHUNK)) * 16 + hh * 8;
        const size_t p1 = ((size_t)(2 * dst + 1) * K_CODES + (acode + c * CHUNK)) * 16 + hh * 8;
        a0hB = *(const bf16x8*)(eht + p0);
        a0lB = *(const bf16x8*)(elt + p0);
        a1hB = *(const bf16x8*)(eht + p1);
        a1lB = *(const bf16x8*)(elt + p1);
    };

    auto ZSTORE_A = [&](int buf) {
        bf16x8 zh, zl;
        split8v(zfaA, zfbA, zh, zl);
        short* sm = smem[buf];
        *(bf16x8*)(sm + Z_SH + so0) = zh;
        *(bf16x8*)(sm + Z_SL + so0) = zl;
    };
    auto ZSTORE_B = [&](int buf) {
        bf16x8 zh, zl;
        split8v(zfaB, zfbB, zh, zl);
        short* sm = smem[buf];
        *(bf16x8*)(sm + Z_SH + so0) = zh;
        *(bf16x8*)(sm + Z_SL + so0) = zl;
    };

    auto MFMABLK = [&](bf16x8 k0h, bf16x8 k0l, bf16x8 k1h, bf16x8 k1l, const short* sm) {
        __builtin_amdgcn_s_setprio(1);
        {   // kstep 0 (d 0..15 of stage)
            bf16x8 b0h = *(const bf16x8*)(sm + Z_SH + b0);
            bf16x8 b0l = *(const bf16x8*)(sm + Z_SL + b0);
            bf16x8 b1h = *(const bf16x8*)(sm + Z_SH + TILE1 + b0);
            bf16x8 b1l = *(const bf16x8*)(sm + Z_SL + TILE1 + b0);
            MFMA3(acc[0], k0h, k0l, b0h, b0l);
            MFMA3(acc[1], k0h, k0l, b1h, b1l);
        }
        {   // kstep 1 (d 16..31)
            bf16x8 b0h = *(const bf16x8*)(sm + Z_SH + b1);
            bf16x8 b0l = *(const bf16x8*)(sm + Z_SL + b1);
            bf16x8 b1h = *(const bf16x8*)(sm + Z_SH + TILE1 + b1);
            bf16x8 b1l = *(const bf16x8*)(sm + Z_SL + TILE1 + b1);
            MFMA3(acc[0], k1h, k1l, b0h, b0l);
            MFMA3(acc[1], k1h, k1l, b1h, b1l);
        }
        __builtin_amdgcn_s_setprio(0);
    };

    // prologue: e2 table; z stages 0 (A) and 1 (B) in flight; A-frags for
    // stage 0; z stage 0 into buffer 0.
    #pragma unroll
    for (int i = 0; i < SPLITK / 512; i++) {
        int idx = tid + i * 512;
        e2sall[idx] = e2h[cs0 + idx];
    }
    ZISSUE_A(0);
    ZISSUE_B(1);
    AISSUE_A(0);
    ZSTORE_A(0);
    __syncthreads();

    #pragma unroll 2
    for (int s = 0; s < NST; s++) {
        const int cur = s & 1;
        if (s + 2 < NST) {                 // z refill: slot consumed last iter
            if (cur == 0) ZISSUE_A(s + 2); else ZISSUE_B(s + 2);
        }
        {
            const short* sm = smem[cur];
            if (cur == 0) MFMABLK(a0hA, a0lA, a1hA, a1lA, sm);
            else          MFMABLK(a0hB, a0lB, a1hB, a1lB, sm);
        }
        if (s + 1 < NST) {                 // A-frags for next stage (other set)
            if (cur == 0) AISSUE_B(s + 1); else AISSUE_A(s + 1);
        }
        if ((s & 7) == 7) {
            // epilogue for chunk c = s>>3: a = acc - e2/2, top-2 insert, re-zero acc
            const int code0 = cs0 + (s >> 3) * CHUNK;
            const float* e2c = e2sall + (s >> 3) * CHUNK;
            float ev[16];
            #pragma unroll
            for (int r = 0; r < 16; r++)
                ev[r] = e2c[wc * 32 + hh * 4 + (r & 3) + ((r >> 2) << 3)];
            #pragma unroll
            for (int tt = 0; tt < 2; tt++) {
                #pragma unroll
                for (int r = 0; r < 16; r++) {
                    float a = acc[tt][r] - ev[r];
                    int code = code0 + wc * 32 + hh * 4 + (r & 3) + ((r >> 2) << 3);
                    if (a > m1[tt]) { m2[tt] = m1[tt]; m1[tt] = a; k1[tt] = code; }
                    else if (a > m2[tt]) m2[tt] = a;
                }
            }
            #pragma unroll
            for (int j = 0; j < 2; j++)
                #pragma unroll
                for (int r = 0; r < 16; r++) acc[j][r] = 0.f;
        }
        if (s + 1 < NST) {                 // store stage s+1 (zf issued iter s-1)
            if (cur == 0) ZSTORE_B(cur ^ 1); else ZSTORE_A(cur ^ 1);
        }
        // T4 barrier: LDS-write visibility only; vmcnt NOT drained — prefetch
        // loads (zf + A-frags) stay in flight across the barrier. sched_barrier
        // fences next-iteration ds_reads from hoisting above (rule #18).
        asm volatile("s_waitcnt lgkmcnt(0)" ::: "memory");
        __builtin_amdgcn_s_barrier();
        __builtin_amdgcn_sched_barrier(0);
    }

    // merge lane halves (hh=0 vs hh=1: same token column, different code rows)
    #pragma unroll
    for (int tt = 0; tt < 2; tt++) {
        float o1 = __shfl_xor(m1[tt], 32);
        float o2 = __shfl_xor(m2[tt], 32);
        int   oi = __shfl_xor(k1[tt], 32);
        bool take = (o1 > m1[tt]) || (o1 == m1[tt] && oi < k1[tt]);
        float w1 = take ? o1 : m1[tt];
        int   wi = take ? oi : k1[tt];
        float ls = take ? m1[tt] : o1;
        m2[tt] = fmaxf(fmaxf(m2[tt], o2), ls);
        m1[tt] = w1; k1[tt] = wi;
    }
    // cross-wave merge: waves wc=0..3 share tokens (wt fixed per wave)
    __syncthreads();
    if (wc == 0 && lane < 32) {
        #pragma unroll
        for (int tt = 0; tt < 2; tt++) {
            int tl = wt * 64 + tt * 32 + lane;
            s1m[tl] = m1[tt]; s2m[tl] = m2[tt]; i1m[tl] = k1[tt];
        }
    }
    __syncthreads();
    #pragma unroll
    for (int mw = 1; mw < 3; mw++) {
        if (wc == mw && lane < 32) {
            #pragma unroll
            for (int tt = 0; tt < 2; tt++) {
                int tl = wt * 64 + tt * 32 + lane;
                float a1 = s1m[tl], a2 = s2m[tl]; int ai = i1m[tl];
                bool take = (a1 > m1[tt]) || (a1 == m1[tt] && ai < k1[tt]);
                float w1 = take ? a1 : m1[tt];
                int   wi = take ? ai : k1[tt];
                float ls = take ? m1[tt] : a1;
                float w2 = fmaxf(fmaxf(m2[tt], a2), ls);
                s1m[tl] = w1; s2m[tl] = w2; i1m[tl] = wi;
            }
        }
        __syncthreads();
    }
    if (wc == 3 && lane < 32) {
        #pragma unroll
        for (int tt = 0; tt < 2; tt++) {
            int tl = wt * 64 + tt * 32 + lane;
            float a1 = s1m[tl], a2 = s2m[tl]; int ai = i1m[tl];
            bool take = (a1 > m1[tt]) || (a1 == m1[tt] && ai < k1[tt]);
            float w1 = take ? a1 : m1[tt];
            int   wi = take ? ai : k1[tt];
            float ls = take ? m1[tt] : a1;
            float w2 = fmaxf(fmaxf(m2[tt], a2), ls);
            size_t t = (size_t)(tok0 + tl) * NSPLIT + split;
            m1a[t] = w1; m2a[t] = w2; i1a[t] = wi;
        }
    }
}

// ---------------- merge splits, detect contested, zero cand counters ----------------
__global__ __launch_bounds__(256) void merge_kernel(
    const float* __restrict__ m1a, const float* __restrict__ m2a,
    const int* __restrict__ i1a, float* __restrict__ m1f,
    int* __restrict__ idxf, int* __restrict__ clist,
    unsigned* __restrict__ ccount, unsigned* __restrict__ ccnt_g)
{
    int t = blockIdx.x * 256 + threadIdx.x;
    ccnt_g[t] = 0u;
    float w1 = m1a[t * NSPLIT], w2 = m2a[t * NSPLIT];
    int   wi = i1a[t * NSPLIT];
    #pragma unroll
    for (int s = 1; s < NSPLIT; s++) {
        float a1 = m1a[t * NSPLIT + s], a2 = m2a[t * NSPLIT + s];
        int   ai = i1a[t * NSPLIT + s];
        bool take = (a1 > w1) || (a1 == w1 && ai < wi);
        float n1 = take ? a1 : w1;
        int   ni = take ? ai : wi;
        float ls = take ? w1 : a1;
        w2 = fmaxf(fmaxf(w2, a2), ls);
        w1 = n1; wi = ni;
    }
    idxf[t] = wi; m1f[t] = w1;
    if (w1 - w2 < CTAU_M) {
        unsigned p = atomicAdd(ccount, 1u);
        clist[p] = t;
    }
}

// LDS short-offsets (rescue): ESH=0 ESL=4096 ZSH=8192 ZSL=9216
#define R_ESH 0
#define R_ESL 4096
#define R_ZSH 8192
#define R_ZSL 9216

// ---------------- rescue: parallel mfma candidate sweep (32 tok x 1024 codes) ----------------
__global__ __launch_bounds__(256) void rescue_kernel(
    const float* __restrict__ zf,
    const short* __restrict__ ehi, const short* __restrict__ elo,
    const float* __restrict__ e2h, const float* __restrict__ m1f,
    const unsigned* __restrict__ ccount, const int* __restrict__ clist,
    unsigned* __restrict__ ccnt_g, int* __restrict__ cand_g)
{
    const unsigned count = *ccount;
    const unsigned base  = blockIdx.x * RBTOK;
    if (base >= count) return;
    const int nt = min(RBTOK, (int)(count - base));
    const int sp = blockIdx.y;

    __shared__ __align__(16) short rsm[10240];   // 20 KB
    __shared__ int   tls[RBTOK];
    __shared__ float thr[RBTOK];
    __shared__ float e2s[CHUNK];

    const int tid  = threadIdx.x;
    const int lane = tid & 63;
    const int w    = tid >> 6;

    if (tid < RBTOK) {
        int s = (tid < nt) ? tid : (nt - 1);
        int t = clist[base + s];
        tls[tid] = t;
        thr[tid] = (tid < nt) ? (m1f[t] - CAND_MM) : FLT_MAX;
    }
    __syncthreads();

    const int l31 = lane & 31, hh = lane >> 5;
    const float mythr = thr[l31];
    const int   mytok = tls[l31];
    const int swz = (l31 >> 1) & 3;
    const int arow = (w * 32 + l31) * 32;
    const int brow = l31 * 32;
    const int a0 = arow + ((hh ^ swz) << 3);
    const int a1 = arow + (((2 + hh) ^ swz) << 3);
    const int b0 = brow + ((hh ^ swz) << 3);
    const int b1 = brow + (((2 + hh) ^ swz) << 3);

    // e staging: 2 slots/thread (pure copies); z: tid<128, one slot each (hi+lo)
    const int er0 = tid >> 2, eq0 = tid & 3;
    const int er1 = er0 + 64;
    const int eso0 = er0 * 32 + ((eq0 ^ ((er0 >> 1) & 3)) << 3);
    const int eso1 = er1 * 32 + ((eq0 ^ ((er1 >> 1) & 3)) << 3);
    const int zr = (tid & 127) >> 2, zq = tid & 3;
    const int zso = zr * 32 + ((zq ^ ((zr >> 1) & 3)) << 3);

    for (int c = 0; c < RSPLIT / CHUNK; c++) {
        const int code0 = sp * RSPLIT + c * CHUNK;
        const float e2v = (tid < CHUNK) ? e2h[code0 + tid] : 0.f;
        f32x16 acc;
        #pragma unroll
        for (int r = 0; r < 16; r++) acc[r] = 0.f;

        for (int st = 0; st < 8; st++) {
            const int d0 = st * 32;
            const size_t ei0 = ((size_t)(code0 + er0) << 8) + d0 + (eq0 << 3);
            const size_t ei1 = ((size_t)(code0 + er1) << 8) + d0 + (eq0 << 3);
            bf16x8 eh0 = *(const bf16x8*)(ehi + ei0);
            bf16x8 el0 = *(const bf16x8*)(elo + ei0);
            bf16x8 eh1 = *(const bf16x8*)(ehi + ei1);
            bf16x8 el1 = *(const bf16x8*)(elo + ei1);
            bf16x8 zh = {}, zl = {};
            if (tid < 128) {
                const size_t zi = ((size_t)tls[zr] << 8) + d0 + (zq << 3);
                float4 za = *(const float4*)(zf + zi);
                float4 zb = *(const float4*)(zf + zi + 4);
                split8v(za, zb, zh, zl);
            }
            __syncthreads();
            *(bf16x8*)(rsm + R_ESH + eso0) = eh0;
            *(bf16x8*)(rsm + R_ESL + eso0) = el0;
            *(bf16x8*)(rsm + R_ESH + eso1) = eh1;
            *(bf16x8*)(rsm + R_ESL + eso1) = el1;
            if (tid < 128) {
                *(bf16x8*)(rsm + R_ZSH + zso) = zh;
                *(bf16x8*)(rsm + R_ZSL + zso) = zl;
            }
            if (st == 0 && tid < CHUNK) e2s[tid] = e2v;
            __syncthreads();
            {
                bf16x8 ah = *(const bf16x8*)(rsm + R_ESH + a0);
                bf16x8 al = *(const bf16x8*)(rsm + R_ESL + a0);
                bf16x8 bh = *(const bf16x8*)(rsm + R_ZSH + b0);
                bf16x8 bl = *(const bf16x8*)(rsm + R_ZSL + b0);
                MFMA3(acc, ah, al, bh, bl);
            }
            {
                bf16x8 ah = *(const bf16x8*)(rsm + R_ESH + a1);
                bf16x8 al = *(const bf16x8*)(rsm + R_ESL + a1);
                bf16x8 bh = *(const bf16x8*)(rsm + R_ZSH + b1);
                bf16x8 bl = *(const bf16x8*)(rsm + R_ZSL + b1);
                MFMA3(acc, ah, al, bh, bl);
            }
        }
        #pragma unroll
        for (int r = 0; r < 16; r++) {
            const int local = w * 32 + hh * 4 + (r & 3) + ((r >> 2) << 3);
            float a = acc[r] - e2s[local];
            if (a >= mythr) {
                unsigned p = atomicAdd(&ccnt_g[mytok], 1u);
                if (p < MAXCAND) cand_g[(size_t)mytok * MAXCAND + p] = code0 + local;
            }
        }
    }
}

// ---------------- resolve: np-exact d over candidates, first-index min ----------------
__global__ __launch_bounds__(256) void resolve_kernel(
    const float* __restrict__ z, const float* __restrict__ emb,
    const float* __restrict__ e2np, const float* __restrict__ Cnp,
    const unsigned* __restrict__ ccount, const int* __restrict__ clist,
    const unsigned* __restrict__ ccnt_g, const int* __restrict__ cand_g,
    int* __restrict__ idxf)
{
    const unsigned count = *ccount;
    const int lane = threadIdx.x & 63;
    const int w    = threadIdx.x >> 6;
    for (unsigned c = blockIdx.x * 4 + w; c < count; c += gridDim.x * 4) {
        const int t = clist[c];
        const int n = (int)min(ccnt_g[t], (unsigned)MAXCAND);
        float bd = FLT_MAX; int bk = 0x7fffffff;
        if (lane < n) {
            const int k = cand_g[(size_t)t * MAXCAND + lane];
            float g = np_einsum256(z + (size_t)t * D_DIM, emb + (size_t)k * D_DIM);
            bd = np_dtilde(Cnp[t], e2np[k], g);
            bk = k;
        }
        #pragma unroll
        for (int off = 32; off >= 1; off >>= 1) {
            float od = __shfl_xor(bd, off);
            int   ok = __shfl_xor(bk, off);
            if (od < bd || (od == bd && ok < bk)) { bd = od; bk = ok; }
        }
        if (lane == 0 && n > 0) idxf[t] = bk;
    }
}

// ---------------- gather z_q, write out0, fp64 MSE sum ----------------
__global__ __launch_bounds__(256) void out_loss_kernel(
    const float* __restrict__ z, const float* __restrict__ emb,
    const int* __restrict__ idxf, float* __restrict__ out0,
    double* __restrict__ loss_sum)
{
    const int total4 = N_TOK * (D_DIM / 4);
    double lsum = 0.0;
    for (int p = blockIdx.x * 256 + threadIdx.x; p < total4; p += gridDim.x * 256) {
        const int n  = p >> 6;
        const int d4 = p & 63;
        const int k  = idxf[n];
        float4 zv = ((const float4*)z)[p];
        float4 ev = ((const float4*)(emb + (size_t)k * D_DIM))[d4];
        float dx = ev.x - zv.x, dy = ev.y - zv.y,
              dz = ev.z - zv.z, dw = ev.w - zv.w;
        float4 o;
        o.x = zv.x + dx; o.y = zv.y + dy; o.z = zv.z + dz; o.w = zv.w + dw;
        ((float4*)out0)[p] = o;
        lsum += (double)dx * dx + (double)dy * dy
              + (double)dz * dz + (double)dw * dw;
    }
    #pragma unroll
    for (int off = 32; off >= 1; off >>= 1) lsum += __shfl_xor(lsum, off);
    __shared__ double wsum[4];
    const int wv = threadIdx.x >> 6;
    if ((threadIdx.x & 63) == 0) wsum[wv] = lsum;
    __syncthreads();
    if (threadIdx.x == 0)
        atomicAdd(loss_sum, wsum[0] + wsum[1] + wsum[2] + wsum[3]);
}

__global__ __launch_bounds__(256) void finalize_kernel(
    const int* __restrict__ idxf, const double* __restrict__ loss_sum,
    float* __restrict__ out)
{
    const int t = blockIdx.x * 256 + threadIdx.x;
    if (t < N_TOK) out[8388611 + t] = (float)idxf[t];
    if (t == 0) {
        double mse = *loss_sum * (1.0 / 8388608.0);
        out[8388608] = (float)(1.25 * mse);
        out[8388609] = (float)(0.25 * mse);
        out[8388610] = (float)mse;
    }
}

extern "C" void kernel_launch(void* const* d_in, const int* in_sizes, int n_in,
                              void* d_out, int out_size, void* d_ws, size_t ws_size,
                              hipStream_t stream)
{
    const float* z   = (const float*)d_in[0];
    const float* emb = (const float*)d_in[1];
    float* out = (float*)d_out;
    char*  ws  = (char*)d_ws;
    char*  ob  = (char*)d_out;

    // big scratch inside d_out (all reads finish before out_loss/finalize rewrite it)
    short*    ehi    = (short*)(ob + 0);
    short*    elo    = (short*)(ob + 4194304);
    short*    eht    = (short*)(ob + 8388608);
    short*    elt    = (short*)(ob + 12582912);
    float*    m1a    = (float*)(ob + 16777216);
    float*    m2a    = (float*)(ob + 17301504);
    int*      i1a    = (int*)(ob + 17825792);
    int*      cand_g = (int*)(ob + 18350080);

    double*   loss_sum = (double*)(ws + 0);
    unsigned* ccount   = (unsigned*)(ws + 8);
    float*    e2np     = (float*)(ws + 16);
    float*    e2h      = (float*)(ws + 32784);
    float*    Cnp      = (float*)(ws + 65552);
    float*    m1f      = (float*)(ws + 196624);
    int*      idxf     = (int*)(ws + 327696);
    int*      clist    = (int*)(ws + 458768);
    unsigned* ccnt_g   = (unsigned*)(ws + 589840);

    prep_e_kernel<<<dim3(K_CODES / 256), dim3(256), 0, stream>>>(
        emb, e2np, e2h, ccount, loss_sum);
    prep_z_kernel<<<dim3(N_TOK / 256), dim3(256), 0, stream>>>(z, Cnp);
    cvt_e_kernel<<<dim3(K_CODES * D_DIM / 8 / 256), dim3(256), 0, stream>>>(
        emb, ehi, elo, eht, elt);
    bulk_kernel<<<dim3((N_TOK / BTOK) * NSPLIT), dim3(512), 0, stream>>>(
        z, eht, elt, e2h, m1a, m2a, i1a);
    merge_kernel<<<dim3(N_TOK / 256), dim3(256), 0, stream>>>(
        m1a, m2a, i1a, m1f, idxf, clist, ccount, ccnt_g);
    rescue_kernel<<<dim3(N_TOK / RBTOK, NRS), dim3(256), 0, stream>>>(
        z, ehi, elo, e2h, m1f, ccount, clist, ccnt_g, cand_g);
    resolve_kernel<<<dim3(128), dim3(256), 0, stream>>>(
        z, emb, e2np, Cnp, ccount, clist, ccnt_g, cand_g, idxf);
    out_loss_kernel<<<dim3(1024), dim3(256), 0, stream>>>(
        z, emb, idxf, out, loss_sum);
    finalize_kernel<<<dim3(N_TOK / 256), dim3(256), 0, stream>>>(
        idxf, loss_sum, out);
}

// Round 10
// 760.334 us; speedup vs baseline: 1.2190x; 1.0088x over previous
//
#include <hip/hip_runtime.h>
#include <hip/hip_bf16.h>
#include <cfloat>

#define N_TOK   32768
#define K_CODES 8192
#define D_DIM   256
#define BTOK    128        // tokens per bulk block
#define CHUNK   128        // codes per chunk
#define NSPLIT  4          // code-range splits in bulk
#define SPLITK  (K_CODES / NSPLIT)
#define CTAU_M  3.0e-5f    // contested if (m1-m2) < this (acc units)
#define CAND_MM 2.4e-5f    // rescue candidate window (acc units)
#define MAXCAND 16
#define RBTOK   32         // tokens per rescue block
#define NRS     8          // code splits in rescue
#define RSPLIT  (K_CODES / NRS)

typedef __attribute__((ext_vector_type(4)))  short bf16x4;
typedef __attribute__((ext_vector_type(8)))  short bf16x8;
typedef __attribute__((ext_vector_type(16))) float f32x16;

// ws layout (bytes) — 720,912 B total (unchanged):
//   0      double loss_sum ; 8 uint ccount (+pad)
//   16     float e2np[8192]
//   32784  float e2h[8192]      0.5*e2np
//   65552  float Cnp[32768]
//   196624 float m1f[32768]
//   327696 int   idxf[32768]
//   458768 int   clist[32768]
//   589840 uint  ccnt_g[32768]   -> end 720912
//
// d_out scratch (33,685,516 B buffer; fully rewritten by out_loss/finalize after
// all scratch reads complete — stream-ordered). zhi scratch REMOVED (zh/zl are
// recomputed in-reg from zf via split8v — bit-identical, proven R9):
//   0        short ehi[8192*256]   (4,194,304)
//   4194304  short elo[8192*256]   (4,194,304)
//   8388608  float m1a[32768*4]    (524,288)
//   8912896  float m2a[32768*4]    (524,288)
//   9437184  int   i1a[32768*4]    (524,288)
//   9961472  int   cand_g[32768*16](2,097,152) -> end 12,058,624 < 33,685,516

// ======== numpy bit-exact fp32 emulation (NO fma contraction) ========
__device__ __forceinline__ float np_sumsq256(const float* __restrict__ row) {
    #pragma clang fp contract(off)
    float blk[2];
    #pragma unroll
    for (int b = 0; b < 2; b++) {
        const float* x = row + b * 128;
        float r[8];
        #pragma unroll
        for (int j = 0; j < 8; j++) { float v = x[j]; r[j] = v * v; }
        for (int i = 8; i < 128; i += 8) {
            #pragma unroll
            for (int j = 0; j < 8; j++) { float v = x[i + j]; r[j] += v * v; }
        }
        blk[b] = ((r[0] + r[1]) + (r[2] + r[3])) + ((r[4] + r[5]) + (r[6] + r[7]));
    }
    return blk[0] + blk[1];
}

__device__ __forceinline__ float np_einsum256(const float* __restrict__ a,
                                              const float* __restrict__ b) {
    #pragma clang fp contract(off)
    float A0 = 0.f, A1 = 0.f, A2 = 0.f, A3 = 0.f;
    for (int m = 0; m < 256; m += 16) {
        A0 = a[m+ 0]*b[m+ 0] + (a[m+ 4]*b[m+ 4] + (a[m+ 8]*b[m+ 8] + (a[m+12]*b[m+12] + A0)));
        A1 = a[m+ 1]*b[m+ 1] + (a[m+ 5]*b[m+ 5] + (a[m+ 9]*b[m+ 9] + (a[m+13]*b[m+13] + A1)));
        A2 = a[m+ 2]*b[m+ 2] + (a[m+ 6]*b[m+ 6] + (a[m+10]*b[m+10] + (a[m+14]*b[m+14] + A2)));
        A3 = a[m+ 3]*b[m+ 3] + (a[m+ 7]*b[m+ 7] + (a[m+11]*b[m+11] + (a[m+15]*b[m+15] + A3)));
    }
    return (A0 + A1) + (A2 + A3);
}

__device__ __forceinline__ float np_dtilde(float Cn, float e2k, float g) {
    #pragma clang fp contract(off)
    float t = Cn + e2k;
    float d = t - 2.0f * g;
    return d;
}

// ======== bf16 split helpers ========
__device__ __forceinline__ unsigned short bf16_rne(float f) {
    unsigned u = __float_as_uint(f);
    unsigned r = u + 0x7fffu + ((u >> 16) & 1u);
    return (unsigned short)(r >> 16);
}
__device__ __forceinline__ void split_bf16(float f, short& hi, short& lo) {
    unsigned short h = bf16_rne(f);
    hi = (short)h;
    float hf = __uint_as_float(((unsigned)h) << 16);
    lo = (short)bf16_rne(f - hf);
}
// full hi+lo split from fp32 source via v_cvt_pk_bf16_f32 (RNE, bit-identical
// to bf16_rne for finite normals). Shared by bulk + rescue so approx scores
// stay mutually bit-consistent (proven absmax=0.0 in R9).
__device__ __forceinline__ void split8v(float4 a, float4 b, bf16x8& h, bf16x8& l) {
    float f[8] = {a.x, a.y, a.z, a.w, b.x, b.y, b.z, b.w};
    #pragma unroll
    for (int i = 0; i < 8; i += 2) {
        __hip_bfloat162 hp = __float22bfloat162_rn(make_float2(f[i], f[i + 1]));
        unsigned hu; __builtin_memcpy(&hu, &hp, 4);
        h[i]     = (short)(hu & 0xffffu);
        h[i + 1] = (short)(hu >> 16);
        float h0 = __uint_as_float(hu << 16);
        float h1 = __uint_as_float(hu & 0xffff0000u);
        __hip_bfloat162 lp = __float22bfloat162_rn(make_float2(f[i] - h0, f[i + 1] - h1));
        unsigned lu; __builtin_memcpy(&lu, &lp, 4);
        l[i]     = (short)(lu & 0xffffu);
        l[i + 1] = (short)(lu >> 16);
    }
}

#define MFMA3(A, ah, al, bh, bl) \
    A = __builtin_amdgcn_mfma_f32_32x32x16_bf16(ah, bh, A, 0, 0, 0); \
    A = __builtin_amdgcn_mfma_f32_32x32x16_bf16(ah, bl, A, 0, 0, 0); \
    A = __builtin_amdgcn_mfma_f32_32x32x16_bf16(al, bh, A, 0, 0, 0);

// ---------------- prep kernels ----------------
__global__ __launch_bounds__(256) void prep_e_kernel(
    const float* __restrict__ emb, float* __restrict__ e2np,
    float* __restrict__ e2h, unsigned* __restrict__ ccount,
    double* __restrict__ loss_sum)
{
    int k = blockIdx.x * 256 + threadIdx.x;
    float v = np_sumsq256(emb + (size_t)k * D_DIM);
    e2np[k] = v;
    e2h[k]  = 0.5f * v;
    if (k == 0) { *ccount = 0u; *loss_sum = 0.0; }
}

__global__ __launch_bounds__(256) void prep_z_kernel(
    const float* __restrict__ z, float* __restrict__ Cnp)
{
    int t = blockIdx.x * 256 + threadIdx.x;
    Cnp[t] = np_sumsq256(z + (size_t)t * D_DIM);
}

// ---------------- one-time conversion into d_out scratch ----------------
__global__ __launch_bounds__(256) void cvt_e_kernel(
    const float* __restrict__ src, short* __restrict__ hi, short* __restrict__ lo)
{
    size_t p = ((size_t)blockIdx.x * 256 + threadIdx.x) * 8;
    float4 v0 = *(const float4*)(src + p);
    float4 v1 = *(const float4*)(src + p + 4);
    short h[8], l[8];
    split_bf16(v0.x, h[0], l[0]); split_bf16(v0.y, h[1], l[1]);
    split_bf16(v0.z, h[2], l[2]); split_bf16(v0.w, h[3], l[3]);
    split_bf16(v1.x, h[4], l[4]); split_bf16(v1.y, h[5], l[5]);
    split_bf16(v1.z, h[6], l[6]); split_bf16(v1.w, h[7], l[7]);
    bf16x8 vh = {h[0],h[1],h[2],h[3],h[4],h[5],h[6],h[7]};
    bf16x8 vl = {l[0],l[1],l[2],l[3],l[4],l[5],l[6],l[7]};
    *(bf16x8*)(hi + p) = vh;
    *(bf16x8*)(lo + p) = vl;
}

// LDS short-offsets (bulk): ESH=0 ESL=4096 ZSH=8192 ZSL=12288; +1024 = +32 rows
#define B_ESH 0
#define B_ESL 4096
#define B_ZSH 8192
#define B_ZSL 12288
#define TILE1 1024

// ---------------- bulk mfma scan: 128 tok x 2048 codes per block ----------------
// R6 structure (best bulk: 504 us): 512 threads / 8 waves, depth-2 reg prefetch,
// T4 barrier (lgkmcnt-only, vmcnt never drained), e2h hoisted to LDS table.
// R10 delta: zhi scratch eliminated — zh/zl computed in-reg from zf (split8v),
// saving one 16B load per thread-stage and the cvt_zhi kernel entirely.
__global__ __launch_bounds__(512, 4) void bulk_kernel(
    const float* __restrict__ zf,
    const short* __restrict__ ehi, const short* __restrict__ elo,
    const float* __restrict__ e2h,
    float* __restrict__ m1a, float* __restrict__ m2a, int* __restrict__ i1a)
{
    __shared__ __align__(16) short smem[2][16384];   // 2 x 32 KB
    __shared__ float e2sall[SPLITK];                 // 2048 floats = 8 KB
    __shared__ float s1m[BTOK], s2m[BTOK];
    __shared__ int   i1m[BTOK];

    const int tid  = threadIdx.x;
    const int lane = tid & 63;
    const int w    = tid >> 6;          // 0..7
    const int wt   = w & 1;             // token 64-half
    const int wc   = w >> 1;            // code 32-tile (0..3)
    const int g     = blockIdx.x & 255;
    const int split = blockIdx.x >> 8;
    const int tok0  = g * BTOK;
    const int cs0   = split * SPLITK;

    // staging: ONE e-slot and ONE z-slot per thread (512 slots = 128 rows x 4 q)
    const int r0 = tid >> 2, q0 = tid & 3;
    const int so0 = r0 * 32 + ((q0 ^ ((r0 >> 1) & 3)) << 3);

    // mfma read addressing (shorts), XOR-swizzled granules
    const int l31 = lane & 31, hh = lane >> 5;
    const int swz = (l31 >> 1) & 3;
    const int arow = (wc * 32 + l31) * 32;      // 32-code tile
    const int brow = (wt * 64 + l31) * 32;      // token half; +TILE1 = +32 rows
    const int a0 = arow + ((hh ^ swz) << 3);
    const int a1 = arow + (((2 + hh) ^ swz) << 3);
    const int b0 = brow + ((hh ^ swz) << 3);
    const int b1 = brow + (((2 + hh) ^ swz) << 3);

    float m1[2] = {-FLT_MAX, -FLT_MAX}, m2[2] = {-FLT_MAX, -FLT_MAX};
    int   k1[2] = {0x7fffffff, 0x7fffffff};

    // depth-2 prefetch register slots (static names — rule #20)
    bf16x8 ehA, elA;  float4 zfaA, zfbA;
    bf16x8 ehB, elB;  float4 zfaB, zfbB;

    f32x16 acc[2];
    #pragma unroll
    for (int j = 0; j < 2; j++)
        #pragma unroll
        for (int r = 0; r < 16; r++) acc[j][r] = 0.f;

    const int NST = (SPLITK / CHUNK) * 8;   // 128 flat stages (16 chunks x 8)

    auto ISSUE_A = [&](int s) {
        const int code0 = cs0 + (s >> 3) * CHUNK;
        const int d0 = (s & 7) * 32;
        const size_t ei = ((size_t)(code0 + r0) << 8) + d0 + (q0 << 3);
        const size_t zi = ((size_t)(tok0 + r0) << 8) + d0 + (q0 << 3);
        ehA = *(const bf16x8*)(ehi + ei);
        elA = *(const bf16x8*)(elo + ei);
        zfaA = *(const float4*)(zf + zi);
        zfbA = *(const float4*)(zf + zi + 4);
    };
    auto ISSUE_B = [&](int s) {
        const int code0 = cs0 + (s >> 3) * CHUNK;
        const int d0 = (s & 7) * 32;
        const size_t ei = ((size_t)(code0 + r0) << 8) + d0 + (q0 << 3);
        const size_t zi = ((size_t)(tok0 + r0) << 8) + d0 + (q0 << 3);
        ehB = *(const bf16x8*)(ehi + ei);
        elB = *(const bf16x8*)(elo + ei);
        zfaB = *(const float4*)(zf + zi);
        zfbB = *(const float4*)(zf + zi + 4);
    };

    auto STORE_A = [&](int buf) {
        bf16x8 zh, zl;
        split8v(zfaA, zfbA, zh, zl);
        short* sm = smem[buf];
        *(bf16x8*)(sm + B_ESH + so0) = ehA;
        *(bf16x8*)(sm + B_ESL + so0) = elA;
        *(bf16x8*)(sm + B_ZSH + so0) = zh;
        *(bf16x8*)(sm + B_ZSL + so0) = zl;
    };
    auto STORE_B = [&](int buf) {
        bf16x8 zh, zl;
        split8v(zfaB, zfbB, zh, zl);
        short* sm = smem[buf];
        *(bf16x8*)(sm + B_ESH + so0) = ehB;
        *(bf16x8*)(sm + B_ESL + so0) = elB;
        *(bf16x8*)(sm + B_ZSH + so0) = zh;
        *(bf16x8*)(sm + B_ZSL + so0) = zl;
    };

    // prologue: e2 table (whole split), stages 0 (A) and 1 (B) in flight,
    // stage 0 into buffer 0. Full __syncthreads here is fine (once).
    #pragma unroll
    for (int i = 0; i < SPLITK / 512; i++) {
        int idx = tid + i * 512;
        e2sall[idx] = e2h[cs0 + idx];
    }
    ISSUE_A(0);
    ISSUE_B(1);
    STORE_A(0);
    __syncthreads();

    #pragma unroll 2
    for (int s = 0; s < NST; s++) {
        const int cur = s & 1;
        if (s + 2 < NST) {                 // refill the slot consumed last iter
            if (cur == 0) ISSUE_A(s + 2); else ISSUE_B(s + 2);
        }
        {
            const short* sm = smem[cur];
            {   // kstep 0
                bf16x8 ah  = *(const bf16x8*)(sm + B_ESH + a0);
                bf16x8 al  = *(const bf16x8*)(sm + B_ESL + a0);
                bf16x8 b0h = *(const bf16x8*)(sm + B_ZSH + b0);
                bf16x8 b0l = *(const bf16x8*)(sm + B_ZSL + b0);
                bf16x8 b1h = *(const bf16x8*)(sm + B_ZSH + TILE1 + b0);
                bf16x8 b1l = *(const bf16x8*)(sm + B_ZSL + TILE1 + b0);
                MFMA3(acc[0], ah, al, b0h, b0l);
                MFMA3(acc[1], ah, al, b1h, b1l);
            }
            {   // kstep 1
                bf16x8 ah  = *(const bf16x8*)(sm + B_ESH + a1);
                bf16x8 al  = *(const bf16x8*)(sm + B_ESL + a1);
                bf16x8 b0h = *(const bf16x8*)(sm + B_ZSH + b1);
                bf16x8 b0l = *(const bf16x8*)(sm + B_ZSL + b1);
                bf16x8 b1h = *(const bf16x8*)(sm + B_ZSH + TILE1 + b1);
                bf16x8 b1l = *(const bf16x8*)(sm + B_ZSL + TILE1 + b1);
                MFMA3(acc[0], ah, al, b0h, b0l);
                MFMA3(acc[1], ah, al, b1h, b1l);
            }
        }
        if ((s & 7) == 7) {
            // epilogue for chunk c = s>>3: a = acc - e2/2, top-2 insert, re-zero acc
            const int code0 = cs0 + (s >> 3) * CHUNK;
            const float* e2c = e2sall + (s >> 3) * CHUNK;
            float ev[16];
            #pragma unroll
            for (int r = 0; r < 16; r++)
                ev[r] = e2c[wc * 32 + hh * 4 + (r & 3) + ((r >> 2) << 3)];
            #pragma unroll
            for (int tt = 0; tt < 2; tt++) {
                #pragma unroll
                for (int r = 0; r < 16; r++) {
                    float a = acc[tt][r] - ev[r];
                    int code = code0 + wc * 32 + hh * 4 + (r & 3) + ((r >> 2) << 3);
                    if (a > m1[tt]) { m2[tt] = m1[tt]; m1[tt] = a; k1[tt] = code; }
                    else if (a > m2[tt]) m2[tt] = a;
                }
            }
            #pragma unroll
            for (int j = 0; j < 2; j++)
                #pragma unroll
                for (int r = 0; r < 16; r++) acc[j][r] = 0.f;
        }
        if (s + 1 < NST) {                 // store stage s+1 (loads issued iter s-1)
            if (cur == 0) STORE_B(cur ^ 1); else STORE_A(cur ^ 1);
        }
        // T4 barrier: LDS-write visibility only; vmcnt NOT drained — the s+2
        // prefetch loads stay in flight across the barrier. sched_barrier(0)
        // fences next-iteration ds_reads from hoisting above (rule #18).
        asm volatile("s_waitcnt lgkmcnt(0)" ::: "memory");
        __builtin_amdgcn_s_barrier();
        __builtin_amdgcn_sched_barrier(0);
    }

    // merge lane halves (hh=0 vs hh=1: same token column, different code rows)
    #pragma unroll
    for (int tt = 0; tt < 2; tt++) {
        float o1 = __shfl_xor(m1[tt], 32);
        float o2 = __shfl_xor(m2[tt], 32);
        int   oi = __shfl_xor(k1[tt], 32);
        bool take = (o1 > m1[tt]) || (o1 == m1[tt] && oi < k1[tt]);
        float w1 = take ? o1 : m1[tt];
        int   wi = take ? oi : k1[tt];
        float ls = take ? m1[tt] : o1;
        m2[tt] = fmaxf(fmaxf(m2[tt], o2), ls);
        m1[tt] = w1; k1[tt] = wi;
    }
    // cross-wave merge: waves wc=0..3 share tokens (wt fixed per wave)
    __syncthreads();
    if (wc == 0 && lane < 32) {
        #pragma unroll
        for (int tt = 0; tt < 2; tt++) {
            int tl = wt * 64 + tt * 32 + lane;
            s1m[tl] = m1[tt]; s2m[tl] = m2[tt]; i1m[tl] = k1[tt];
        }
    }
    __syncthreads();
    #pragma unroll
    for (int mw = 1; mw < 3; mw++) {
        if (wc == mw && lane < 32) {
            #pragma unroll
            for (int tt = 0; tt < 2; tt++) {
                int tl = wt * 64 + tt * 32 + lane;
                float a1 = s1m[tl], a2 = s2m[tl]; int ai = i1m[tl];
                bool take = (a1 > m1[tt]) || (a1 == m1[tt] && ai < k1[tt]);
                float w1 = take ? a1 : m1[tt];
                int   wi = take ? ai : k1[tt];
                float ls = take ? m1[tt] : a1;
                float w2 = fmaxf(fmaxf(m2[tt], a2), ls);
                s1m[tl] = w1; s2m[tl] = w2; i1m[tl] = wi;
            }
        }
        __syncthreads();
    }
    if (wc == 3 && lane < 32) {
        #pragma unroll
        for (int tt = 0; tt < 2; tt++) {
            int tl = wt * 64 + tt * 32 + lane;
            float a1 = s1m[tl], a2 = s2m[tl]; int ai = i1m[tl];
            bool take = (a1 > m1[tt]) || (a1 == m1[tt] && ai < k1[tt]);
            float w1 = take ? a1 : m1[tt];
            int   wi = take ? ai : k1[tt];
            float ls = take ? m1[tt] : a1;
            float w2 = fmaxf(fmaxf(m2[tt], a2), ls);
            size_t t = (size_t)(tok0 + tl) * NSPLIT + split;
            m1a[t] = w1; m2a[t] = w2; i1a[t] = wi;
        }
    }
}

// ---------------- merge splits, detect contested, zero cand counters ----------------
__global__ __launch_bounds__(256) void merge_kernel(
    const float* __restrict__ m1a, const float* __restrict__ m2a,
    const int* __restrict__ i1a, float* __restrict__ m1f,
    int* __restrict__ idxf, int* __restrict__ clist,
    unsigned* __restrict__ ccount, unsigned* __restrict__ ccnt_g)
{
    int t = blockIdx.x * 256 + threadIdx.x;
    ccnt_g[t] = 0u;
    float w1 = m1a[t * NSPLIT], w2 = m2a[t * NSPLIT];
    int   wi = i1a[t * NSPLIT];
    #pragma unroll
    for (int s = 1; s < NSPLIT; s++) {
        float a1 = m1a[t * NSPLIT + s], a2 = m2a[t * NSPLIT + s];
        int   ai = i1a[t * NSPLIT + s];
        bool take = (a1 > w1) || (a1 == w1 && ai < wi);
        float n1 = take ? a1 : w1;
        int   ni = take ? ai : wi;
        float ls = take ? w1 : a1;
        w2 = fmaxf(fmaxf(w2, a2), ls);
        w1 = n1; wi = ni;
    }
    idxf[t] = wi; m1f[t] = w1;
    if (w1 - w2 < CTAU_M) {
        unsigned p = atomicAdd(ccount, 1u);
        clist[p] = t;
    }
}

// LDS short-offsets (rescue): ESH=0 ESL=4096 ZSH=8192 ZSL=9216
#define R_ESH 0
#define R_ESL 4096
#define R_ZSH 8192
#define R_ZSL 9216

// ---------------- rescue: parallel mfma candidate sweep (32 tok x 1024 codes) ----------------
__global__ __launch_bounds__(256) void rescue_kernel(
    const float* __restrict__ zf,
    const short* __restrict__ ehi, const short* __restrict__ elo,
    const float* __restrict__ e2h, const float* __restrict__ m1f,
    const unsigned* __restrict__ ccount, const int* __restrict__ clist,
    unsigned* __restrict__ ccnt_g, int* __restrict__ cand_g)
{
    const unsigned count = *ccount;
    const unsigned base  = blockIdx.x * RBTOK;
    if (base >= count) return;
    const int nt = min(RBTOK, (int)(count - base));
    const int sp = blockIdx.y;

    __shared__ __align__(16) short rsm[10240];   // 20 KB
    __shared__ int   tls[RBTOK];
    __shared__ float thr[RBTOK];
    __shared__ float e2s[CHUNK];

    const int tid  = threadIdx.x;
    const int lane = tid & 63;
    const int w    = tid >> 6;

    if (tid < RBTOK) {
        int s = (tid < nt) ? tid : (nt - 1);
        int t = clist[base + s];
        tls[tid] = t;
        thr[tid] = (tid < nt) ? (m1f[t] - CAND_MM) : FLT_MAX;
    }
    __syncthreads();

    const int l31 = lane & 31, hh = lane >> 5;
    const float mythr = thr[l31];
    const int   mytok = tls[l31];
    const int swz = (l31 >> 1) & 3;
    const int arow = (w * 32 + l31) * 32;
    const int brow = l31 * 32;
    const int a0 = arow + ((hh ^ swz) << 3);
    const int a1 = arow + (((2 + hh) ^ swz) << 3);
    const int b0 = brow + ((hh ^ swz) << 3);
    const int b1 = brow + (((2 + hh) ^ swz) << 3);

    // e staging: 2 slots/thread (pure copies); z: tid<128, one slot each (hi+lo)
    const int er0 = tid >> 2, eq0 = tid & 3;
    const int er1 = er0 + 64;
    const int eso0 = er0 * 32 + ((eq0 ^ ((er0 >> 1) & 3)) << 3);
    const int eso1 = er1 * 32 + ((eq0 ^ ((er1 >> 1) & 3)) << 3);
    const int zr = (tid & 127) >> 2, zq = tid & 3;
    const int zso = zr * 32 + ((zq ^ ((zr >> 1) & 3)) << 3);

    for (int c = 0; c < RSPLIT / CHUNK; c++) {
        const int code0 = sp * RSPLIT + c * CHUNK;
        const float e2v = (tid < CHUNK) ? e2h[code0 + tid] : 0.f;
        f32x16 acc;
        #pragma unroll
        for (int r = 0; r < 16; r++) acc[r] = 0.f;

        for (int st = 0; st < 8; st++) {
            const int d0 = st * 32;
            const size_t ei0 = ((size_t)(code0 + er0) << 8) + d0 + (eq0 << 3);
            const size_t ei1 = ((size_t)(code0 + er1) << 8) + d0 + (eq0 << 3);
            bf16x8 eh0 = *(const bf16x8*)(ehi + ei0);
            bf16x8 el0 = *(const bf16x8*)(elo + ei0);
            bf16x8 eh1 = *(const bf16x8*)(ehi + ei1);
            bf16x8 el1 = *(const bf16x8*)(elo + ei1);
            bf16x8 zh = {}, zl = {};
            if (tid < 128) {
                const size_t zi = ((size_t)tls[zr] << 8) + d0 + (zq << 3);
                float4 za = *(const float4*)(zf + zi);
                float4 zb = *(const float4*)(zf + zi + 4);
                split8v(za, zb, zh, zl);
            }
            __syncthreads();
            *(bf16x8*)(rsm + R_ESH + eso0) = eh0;
            *(bf16x8*)(rsm + R_ESL + eso0) = el0;
            *(bf16x8*)(rsm + R_ESH + eso1) = eh1;
            *(bf16x8*)(rsm + R_ESL + eso1) = el1;
            if (tid < 128) {
                *(bf16x8*)(rsm + R_ZSH + zso) = zh;
                *(bf16x8*)(rsm + R_ZSL + zso) = zl;
            }
            if (st == 0 && tid < CHUNK) e2s[tid] = e2v;
            __syncthreads();
            {
                bf16x8 ah = *(const bf16x8*)(rsm + R_ESH + a0);
                bf16x8 al = *(const bf16x8*)(rsm + R_ESL + a0);
                bf16x8 bh = *(const bf16x8*)(rsm + R_ZSH + b0);
                bf16x8 bl = *(const bf16x8*)(rsm + R_ZSL + b0);
                MFMA3(acc, ah, al, bh, bl);
            }
            {
                bf16x8 ah = *(const bf16x8*)(rsm + R_ESH + a1);
                bf16x8 al = *(const bf16x8*)(rsm + R_ESL + a1);
                bf16x8 bh = *(const bf16x8*)(rsm + R_ZSH + b1);
                bf16x8 bl = *(const bf16x8*)(rsm + R_ZSL + b1);
                MFMA3(acc, ah, al, bh, bl);
            }
        }
        #pragma unroll
        for (int r = 0; r < 16; r++) {
            const int local = w * 32 + hh * 4 + (r & 3) + ((r >> 2) << 3);
            float a = acc[r] - e2s[local];
            if (a >= mythr) {
                unsigned p = atomicAdd(&ccnt_g[mytok], 1u);
                if (p < MAXCAND) cand_g[(size_t)mytok * MAXCAND + p] = code0 + local;
            }
        }
    }
}

// ---------------- resolve: np-exact d over candidates, first-index min ----------------
__global__ __launch_bounds__(256) void resolve_kernel(
    const float* __restrict__ z, const float* __restrict__ emb,
    const float* __restrict__ e2np, const float* __restrict__ Cnp,
    const unsigned* __restrict__ ccount, const int* __restrict__ clist,
    const unsigned* __restrict__ ccnt_g, const int* __restrict__ cand_g,
    int* __restrict__ idxf)
{
    const unsigned count = *ccount;
    const int lane = threadIdx.x & 63;
    const int w    = threadIdx.x >> 6;
    for (unsigned c = blockIdx.x * 4 + w; c < count; c += gridDim.x * 4) {
        const int t = clist[c];
        const int n = (int)min(ccnt_g[t], (unsigned)MAXCAND);
        float bd = FLT_MAX; int bk = 0x7fffffff;
        if (lane < n) {
            const int k = cand_g[(size_t)t * MAXCAND + lane];
            float g = np_einsum256(z + (size_t)t * D_DIM, emb + (size_t)k * D_DIM);
            bd = np_dtilde(Cnp[t], e2np[k], g);
            bk = k;
        }
        #pragma unroll
        for (int off = 32; off >= 1; off >>= 1) {
            float od = __shfl_xor(bd, off);
            int   ok = __shfl_xor(bk, off);
            if (od < bd || (od == bd && ok < bk)) { bd = od; bk = ok; }
        }
        if (lane == 0 && n > 0) idxf[t] = bk;
    }
}

// ---------------- gather z_q, write out0, fp64 MSE sum ----------------
__global__ __launch_bounds__(256) void out_loss_kernel(
    const float* __restrict__ z, const float* __restrict__ emb,
    const int* __restrict__ idxf, float* __restrict__ out0,
    double* __restrict__ loss_sum)
{
    const int total4 = N_TOK * (D_DIM / 4);
    double lsum = 0.0;
    for (int p = blockIdx.x * 256 + threadIdx.x; p < total4; p += gridDim.x * 256) {
        const int n  = p >> 6;
        const int d4 = p & 63;
        const int k  = idxf[n];
        float4 zv = ((const float4*)z)[p];
        float4 ev = ((const float4*)(emb + (size_t)k * D_DIM))[d4];
        float dx = ev.x - zv.x, dy = ev.y - zv.y,
              dz = ev.z - zv.z, dw = ev.w - zv.w;
        float4 o;
        o.x = zv.x + dx; o.y = zv.y + dy; o.z = zv.z + dz; o.w = zv.w + dw;
        ((float4*)out0)[p] = o;
        lsum += (double)dx * dx + (double)dy * dy
              + (double)dz * dz + (double)dw * dw;
    }
    #pragma unroll
    for (int off = 32; off >= 1; off >>= 1) lsum += __shfl_xor(lsum, off);
    __shared__ double wsum[4];
    const int wv = threadIdx.x >> 6;
    if ((threadIdx.x & 63) == 0) wsum[wv] = lsum;
    __syncthreads();
    if (threadIdx.x == 0)
        atomicAdd(loss_sum, wsum[0] + wsum[1] + wsum[2] + wsum[3]);
}

__global__ __launch_bounds__(256) void finalize_kernel(
    const int* __restrict__ idxf, const double* __restrict__ loss_sum,
    float* __restrict__ out)
{
    const int t = blockIdx.x * 256 + threadIdx.x;
    if (t < N_TOK) out[8388611 + t] = (float)idxf[t];
    if (t == 0) {
        double mse = *loss_sum * (1.0 / 8388608.0);
        out[8388608] = (float)(1.25 * mse);
        out[8388609] = (float)(0.25 * mse);
        out[8388610] = (float)mse;
    }
}

extern "C" void kernel_launch(void* const* d_in, const int* in_sizes, int n_in,
                              void* d_out, int out_size, void* d_ws, size_t ws_size,
                              hipStream_t stream)
{
    const float* z   = (const float*)d_in[0];
    const float* emb = (const float*)d_in[1];
    float* out = (float*)d_out;
    char*  ws  = (char*)d_ws;
    char*  ob  = (char*)d_out;

    // big scratch inside d_out (all reads finish before out_loss/finalize rewrite it)
    short*    ehi    = (short*)(ob + 0);
    short*    elo    = (short*)(ob + 4194304);
    float*    m1a    = (float*)(ob + 8388608);
    float*    m2a    = (float*)(ob + 8912896);
    int*      i1a    = (int*)(ob + 9437184);
    int*      cand_g = (int*)(ob + 9961472);

    double*   loss_sum = (double*)(ws + 0);
    unsigned* ccount   = (unsigned*)(ws + 8);
    float*    e2np     = (float*)(ws + 16);
    float*    e2h      = (float*)(ws + 32784);
    float*    Cnp      = (float*)(ws + 65552);
    float*    m1f      = (float*)(ws + 196624);
    int*      idxf     = (int*)(ws + 327696);
    int*      clist    = (int*)(ws + 458768);
    unsigned* ccnt_g   = (unsigned*)(ws + 589840);

    prep_e_kernel<<<dim3(K_CODES / 256), dim3(256), 0, stream>>>(
        emb, e2np, e2h, ccount, loss_sum);
    prep_z_kernel<<<dim3(N_TOK / 256), dim3(256), 0, stream>>>(z, Cnp);
    cvt_e_kernel<<<dim3(K_CODES * D_DIM / 8 / 256), dim3(256), 0, stream>>>(emb, ehi, elo);
    bulk_kernel<<<dim3((N_TOK / BTOK) * NSPLIT), dim3(512), 0, stream>>>(
        z, ehi, elo, e2h, m1a, m2a, i1a);
    merge_kernel<<<dim3(N_TOK / 256), dim3(256), 0, stream>>>(
        m1a, m2a, i1a, m1f, idxf, clist, ccount, ccnt_g);
    rescue_kernel<<<dim3(N_TOK / RBTOK, NRS), dim3(256), 0, stream>>>(
        z, ehi, elo, e2h, m1f, ccount, clist, ccnt_g, cand_g);
    resolve_kernel<<<dim3(128), dim3(256), 0, stream>>>(
        z, emb, e2np, Cnp, ccount, clist, ccnt_g, cand_g, idxf);
    out_loss_kernel<<<dim3(1024), dim3(256), 0, stream>>>(
        z, emb, idxf, out, loss_sum);
    finalize_kernel<<<dim3(N_TOK / 256), dim3(256), 0, stream>>>(
        idxf, loss_sum, out);
}